// Round 17
// baseline (840.754 us; speedup 1.0000x reference)
//
#include <hip/hip_runtime.h>
#include <math.h>

#define T_LEN 4096
#define D_DIM 1024
#define B_DIM 4
#define N_STAGES 3
#define FT 512          // threads for FFT kernels

typedef unsigned short bf16_t;
typedef __bf16 bf16x8 __attribute__((ext_vector_type(8)));
typedef float f32x4 __attribute__((ext_vector_type(4)));

// LDS bank swizzle at float2 granularity — R10/R15-verified conflict floor.
#define SW(i) ((i) ^ ((((unsigned)(i)) >> 4) & 15))

// ---------------------------------------------------------------- helpers
__device__ __forceinline__ bf16_t f2bf(float f) {
    union { float f; unsigned u; } v; v.f = f;
    unsigned r = v.u + 0x7FFFu + ((v.u >> 16) & 1u);   // round-nearest-even
    return (bf16_t)(r >> 16);
}
__device__ __forceinline__ float bf2f(bf16_t h) {
    union { unsigned u; float f; } v; v.u = ((unsigned)h) << 16;
    return v.f;
}
__device__ __forceinline__ float2 cmul(float2 a, float2 b) {
    return make_float2(a.x * b.x - a.y * b.y, a.x * b.y + a.y * b.x);
}
__device__ __forceinline__ float2 cadd(float2 a, float2 b) { return make_float2(a.x + b.x, a.y + b.y); }
__device__ __forceinline__ float2 csub(float2 a, float2 b) { return make_float2(a.x - b.x, a.y - b.y); }
__device__ __forceinline__ float2 conjf2(float2 a) { return make_float2(a.x, -a.y); }

#define GLOAD_LDS16(gp, lp) __builtin_amdgcn_global_load_lds( \
    (const __attribute__((address_space(1))) void*)(gp),      \
    (__attribute__((address_space(3))) void*)(lp), 16, 0, 0)

// ---------------------------------------------------------------- pos encoding (bf16 out)
__global__ __launch_bounds__(256) void pos_kernel(bf16_t* __restrict__ posbf) {
    int idx = blockIdx.x * 256 + threadIdx.x;
    int t = idx >> 10;
    int k = idx & 1023;
    float e = (float)(k & ~1) / (float)D_DIM;
    float r = exp2f(-e * 13.287712379549449f);          // 10000^-e
    float angle = (float)t * r;
    float v = (k & 1) ? cosf(angle) : sinf(angle);
    posbf[idx] = f2bf(v);
}

// ---------------------------------------------------------------- twiddle tables -> global (L2-resident)
// gW4[j] = exp(-2*pi*i*j/4096), j in [0,512)   (radix-8 pass twiddles, jm<512)
// gW8[k] = exp(-pi*i*k/4096),  k in [0,2048)   (real-FFT untangle twiddles)
__global__ __launch_bounds__(256) void twiddle_init_kernel(float2* __restrict__ gW4,
                                                           float2* __restrict__ gW8) {
    int i = blockIdx.x * 256 + threadIdx.x;   // 0..2559
    if (i < 512) {
        float sn, cs;
        __sincosf((float)i * -1.5339807878856412e-3f, &sn, &cs);   // -2*pi/4096
        gW4[i] = make_float2(cs, sn);
    } else if (i < 2560) {
        int k = i - 512;
        float sn, cs;
        __sincosf((float)k * -7.669903939428206e-4f, &sn, &cs);    // -pi/4096
        gW8[k] = make_float2(cs, sn);
    }
}

// ---------------------------------------------------------------- f32 -> bf16 copy
__global__ __launch_bounds__(256) void f32_to_bf16_kernel(const float* __restrict__ in,
                                                          bf16_t* __restrict__ out, int n8) {
    int i = blockIdx.x * 256 + threadIdx.x;
    if (i >= n8) return;
    float4 a = ((const float4*)in)[i * 2];
    float4 b = ((const float4*)in)[i * 2 + 1];
    ((ushort4*)out)[i * 2]     = make_ushort4(f2bf(a.x), f2bf(a.y), f2bf(a.z), f2bf(a.w));
    ((ushort4*)out)[i * 2 + 1] = make_ushort4(f2bf(b.x), f2bf(b.y), f2bf(b.z), f2bf(b.w));
}

// ---------------------------------------------------------------- W [K][N] f32 -> WT [N][K] bf16
__global__ __launch_bounds__(256) void transpose_to_bf16(const float* __restrict__ in,
                                                         bf16_t* __restrict__ out, int K, int N) {
    __shared__ float tile[32][33];
    const int n0 = blockIdx.x * 32;
    const int k0 = blockIdx.y * 32;
    const int tx = threadIdx.x & 31;
    const int ty = threadIdx.x >> 5;
    for (int i = ty; i < 32; i += 8)
        tile[i][tx] = in[(size_t)(k0 + i) * N + n0 + tx];
    __syncthreads();
    for (int i = ty; i < 32; i += 8)
        out[(size_t)(n0 + i) * K + k0 + tx] = f2bf(tile[tx][i]);
}

// ---------------------------------------------------------------- bf16 MFMA GEMM (m97 structure)
template <int MODE>
__global__ __launch_bounds__(256) void mfma_gemm(const bf16_t* __restrict__ A,
                                                 const bf16_t* __restrict__ BT,
                                                 const float* __restrict__ bias,
                                                 void* __restrict__ outv,
                                                 int M, int N, int K, int nbx) {
    constexpr int SMEM_BYTES = (MODE == 0) ? (128 * 136 * 2) : (128 * 132 * 4);
    __shared__ __align__(16) char smem[SMEM_BYTES];
    bf16_t* As = (bf16_t*)smem;
    bf16_t* Bs = (bf16_t*)(smem + 8192);

    const int tid = threadIdx.x;
    const int lane = tid & 63;
    const int w = tid >> 6;
    const int wr = w >> 1, wc = w & 1;

    const int nwg = gridDim.x;
    const int q = nwg >> 3;
    const int swz = (blockIdx.x & 7) * q + (blockIdx.x >> 3);
    const int by = swz / nbx, bx = swz - by * nbx;
    const int row0 = by * 128, col0 = bx * 128;

    f32x4 acc[4][4];
#pragma unroll
    for (int m = 0; m < 4; ++m)
#pragma unroll
        for (int n = 0; n < 4; ++n) acc[m][n] = (f32x4)(0.0f);

    int offs[2], rr[2], kk8[2];
#pragma unroll
    for (int c = 0; c < 2; ++c) {
        offs[c] = (w * 2 + c) * 1024 + lane * 16;
        rr[c] = offs[c] >> 6;
        kk8[c] = ((offs[c] >> 4) & 3) * 8;
    }

    for (int k0 = 0; k0 < K; k0 += 32) {
#pragma unroll
        for (int c = 0; c < 2; ++c) {
            const bf16_t* gA = A + (size_t)(row0 + rr[c]) * K + k0 + kk8[c];
            GLOAD_LDS16(gA, As + (w * 2 + c) * 512);
            const bf16_t* gB = BT + (size_t)(col0 + rr[c]) * K + k0 + kk8[c];
            GLOAD_LDS16(gB, Bs + (w * 2 + c) * 512);
        }
        __syncthreads();

        bf16x8 af[4], bfr[4];
#pragma unroll
        for (int m = 0; m < 4; ++m)
            af[m] = *(const bf16x8*)&As[(wr * 64 + m * 16 + (lane & 15)) * 32 + (lane >> 4) * 8];
#pragma unroll
        for (int n = 0; n < 4; ++n)
            bfr[n] = *(const bf16x8*)&Bs[(wc * 64 + n * 16 + (lane & 15)) * 32 + (lane >> 4) * 8];
#pragma unroll
        for (int m = 0; m < 4; ++m)
#pragma unroll
            for (int n = 0; n < 4; ++n)
                acc[m][n] = __builtin_amdgcn_mfma_f32_16x16x32_bf16(af[m], bfr[n], acc[m][n], 0, 0, 0);
        __syncthreads();
    }

    if (MODE == 0) {
        bf16_t* Cs = (bf16_t*)smem;           // [128 cols][pitch 136]
#pragma unroll
        for (int m = 0; m < 4; ++m)
#pragma unroll
            for (int n = 0; n < 4; ++n) {
                int cl = wc * 64 + n * 16 + (lane & 15);
                int rlb = wr * 64 + m * 16 + ((lane >> 4) << 2);
                float bb = bias[col0 + cl];
#pragma unroll
                for (int j = 0; j < 4; ++j)
                    Cs[cl * 136 + rlb + j] = f2bf(acc[m][n][j] + bb);
            }
        __syncthreads();
        int dl = tid >> 1, th = tid & 1;
        int cc = col0 + dl;
        int s = cc >> 10, d = cc & 1023;
        int b = row0 >> 12;
        int t0 = (row0 & 4095) + th * 64;
        uint4* dst = (uint4*)&((bf16_t*)outv)[((size_t)(s * 4 + b) * 1024 + d) * 4096 + t0];
        const uint4* src = (const uint4*)&Cs[dl * 136 + th * 64];
#pragma unroll
        for (int j = 0; j < 8; ++j) dst[j] = src[j];
    } else {
        float* CsF = (float*)smem;            // [128 cols][pitch 132]
#pragma unroll
        for (int m = 0; m < 4; ++m)
#pragma unroll
            for (int n = 0; n < 4; ++n) {
                int cl = wc * 64 + n * 16 + (lane & 15);
                int rlb = wr * 64 + m * 16 + ((lane >> 4) << 2);
                float bb = bias[col0 + cl];
#pragma unroll
                for (int j = 0; j < 4; ++j)
                    CsF[cl * 132 + rlb + j] = acc[m][n][j] + bb;
            }
        __syncthreads();
        int dl = tid >> 1, th = tid & 1;
        int cc = col0 + dl;
        uint4* dst = (uint4*)&((float*)outv)[(size_t)cc * 4096 + row0 + th * 64];
        const uint4* src = (const uint4*)&CsF[dl * 132 + th * 64];
#pragma unroll
        for (int j = 0; j < 16; ++j) dst[j] = src[j];
    }
}

// ---------------------------------------------------------------- radix-8 DFT building blocks
template <int INV>
__device__ __forceinline__ void bfly4(float2& a, float2& b, float2& c, float2& d) {
    float2 t0 = cadd(a, c), t1 = csub(a, c), t2 = cadd(b, d), t3 = csub(b, d);
    float2 it3 = INV ? make_float2(-t3.y, t3.x) : make_float2(t3.y, -t3.x);
    a = cadd(t0, t2); b = cadd(t1, it3); c = csub(t0, t2); d = csub(t1, it3);
}

// in-register DFT-8; on return x[q] = F_q (natural order)
template <int INV>
__device__ __forceinline__ void dft8(float2 (&x)[8]) {
    bfly4<INV>(x[0], x[2], x[4], x[6]);
    bfly4<INV>(x[1], x[3], x[5], x[7]);
    const float s2 = 0.70710678118654752f;
    const float2 o1 = INV ? make_float2(s2, s2) : make_float2(s2, -s2);
    const float2 o3 = INV ? make_float2(-s2, s2) : make_float2(-s2, -s2);
    x[3] = cmul(x[3], o1);
    x[5] = INV ? make_float2(-x[5].y, x[5].x) : make_float2(x[5].y, -x[5].x);
    x[7] = cmul(x[7], o3);
    float2 F0 = cadd(x[0], x[1]), F4 = csub(x[0], x[1]);
    float2 F1 = cadd(x[2], x[3]), F5 = csub(x[2], x[3]);
    float2 F2 = cadd(x[4], x[5]), F6 = csub(x[4], x[5]);
    float2 F3 = cadd(x[6], x[7]), F7 = csub(x[6], x[7]);
    x[0] = F0; x[1] = F1; x[2] = F2; x[3] = F3;
    x[4] = F4; x[5] = F5; x[6] = F6; x[7] = F7;
}

// ---------------------------------------------------------------- 1-seq radix-8 pass, 512 thr, global twiddles
// w1 load issued BEFORE the read barrier so L2 latency hides under dft8.
template <int INV, int M>
__device__ __forceinline__ void r8_pass1g(float2* __restrict__ s,
                                          const float2* __restrict__ gW4) {
    const int p = threadIdx.x;
    const int r = p & (M - 1);
    const int jm = p - r;
    float2 w1;
    if (M != 512) w1 = gW4[jm];             // global load, L2-hot (4 KB table)
    float2 x[8];
#pragma unroll
    for (int c = 0; c < 8; ++c) x[c] = s[SW(p + 512 * c)];
    __syncthreads();
    dft8<INV>(x);
    const int base = 8 * jm + r;
    if (M == 512) {
#pragma unroll
        for (int q = 0; q < 8; ++q) s[SW(base + q * 512)] = x[q];
    } else {
        if (INV) w1.y = -w1.y;
        float2 w2 = cmul(w1, w1);
        float2 w3 = cmul(w2, w1);
        float2 w4 = cmul(w2, w2);
        s[SW(base)]         = x[0];
        s[SW(base + M)]     = cmul(w1, x[1]);
        s[SW(base + 2 * M)] = cmul(w2, x[2]);
        s[SW(base + 3 * M)] = cmul(w3, x[3]);
        s[SW(base + 4 * M)] = cmul(w4, x[4]);
        s[SW(base + 5 * M)] = cmul(cmul(w4, w1), x[5]);
        s[SW(base + 6 * M)] = cmul(cmul(w4, w2), x[6]);
        s[SW(base + 7 * M)] = cmul(cmul(w4, w3), x[7]);
    }
    __syncthreads();
}

template <int INV>
__device__ __forceinline__ void fft4096_1g(float2* __restrict__ s,
                                           const float2* __restrict__ gW4) {
    r8_pass1g<INV, 1>(s, gW4);
    r8_pass1g<INV, 8>(s, gW4);
    r8_pass1g<INV, 64>(s, gW4);
    r8_pass1g<INV, 512>(s, gW4);
}

// spec accessors (half-spectrum rows of 4097 complex, f32 or bf16 pairs)
__device__ __forceinline__ float2 spec_load(const void* spec, int bf, size_t row, int k) {
    if (bf) {
        ushort2 h = ((const ushort2*)spec)[row * 4097 + k];
        return make_float2(bf2f(h.x), bf2f(h.y));
    }
    return ((const float2*)spec)[row * 4097 + k];
}
__device__ __forceinline__ void spec_store(void* spec, int bf, size_t row, int k, float2 v) {
    if (bf) ((ushort2*)spec)[row * 4097 + k] = make_ushort2(f2bf(v.x), f2bf(v.y));
    else    ((float2*)spec)[row * 4097 + k] = v;
}

// ---------------------------------------------------------------- filter spectra (packed real FFT)
// 32,768 B LDS (tables in global) — tests the 2-blocks/CU packing hypothesis.
__global__ __launch_bounds__(FT)
void filter_fft_kernel(const float* __restrict__ fT,
                       void* __restrict__ specv,
                       int spec_bf16,
                       const float2* __restrict__ gW4,
                       const float2* __restrict__ gW8) {
    __shared__ __align__(16) float2 sA[4096];
    const int tid = threadIdx.x;
    const size_t row = blockIdx.x;          // i*1024 + d
    const float4* f4 = (const float4*)&fT[row * T_LEN];
#pragma unroll
    for (int u = 0; u < 2; ++u) {
        int j = u * FT + tid;               // 0..1023
        float4 v = f4[j];
        sA[SW(2 * j)]     = make_float2(v.x, v.y);
        sA[SW(2 * j + 1)] = make_float2(v.z, v.w);
    }
#pragma unroll
    for (int u = 0; u < 4; ++u) {
        int n = 2048 + u * FT + tid;
        sA[SW(n)] = make_float2(0.0f, 0.0f);
    }
    __syncthreads();
    fft4096_1g<0>(sA, gW4);
    // untangle: F[k] = Ye + W_8192^k * Yo ; F[4096-k] = conj(Ye - W^k Yo)
#pragma unroll
    for (int u = 0; u < 4; ++u) {
        int s = u * FT + tid;
        if (s < 2047) {
            int k = s + 1, nk = 4096 - k;
            float2 Zk = sA[SW(k)], Zn = sA[SW(nk)];
            float2 Ye = make_float2(0.5f * (Zk.x + Zn.x), 0.5f * (Zk.y - Zn.y));
            float2 Yo = make_float2(0.5f * (Zk.y + Zn.y), -0.5f * (Zk.x - Zn.x));
            float2 w = gW8[k];
            float2 wYo = cmul(w, Yo);
            spec_store(specv, spec_bf16, row, k, cadd(Ye, wYo));
            spec_store(specv, spec_bf16, row, nk, conjf2(csub(Ye, wYo)));
        }
    }
    if (tid == 0) {
        float2 Z0 = sA[SW(0)];
        spec_store(specv, spec_bf16, row, 0,    make_float2(Z0.x + Z0.y, 0.0f));
        spec_store(specv, spec_bf16, row, 4096, make_float2(Z0.x - Z0.y, 0.0f));
        spec_store(specv, spec_bf16, row, 2048, conjf2(sA[SW(2048)]));
    }
}

// ---------------------------------------------------------------- fused 3-stage conv, 1 seq/block, 512 thr
// Block = (d, bb): grid 4096, d-major so same-d blocks share spec rows in L2.
// LDS exactly 32,768 B (the only config that ever co-scheduled 2 blocks/CU —
// R6 45.6% occ vs 23% for every >32KB config, VGPR/LDS-physical permitting).
__global__ __launch_bounds__(FT)
void conv_kernel(const bf16_t* __restrict__ xpT,
                 const void* __restrict__ specv,
                 int spec_bf16,
                 bf16_t* __restrict__ yT,
                 const float2* __restrict__ gW4,
                 const float2* __restrict__ gW8) {
    __shared__ __align__(16) float2 sA[4096];
    const int tid = threadIdx.x;
    const int d  = blockIdx.x >> 2;         // 0..1023
    const int bb = blockIdx.x & 3;          // seq 0..3

    const ushort4* y4 = (const ushort4*)&xpT[((size_t)bb * 1024 + d) * T_LEN];
#pragma unroll
    for (int u = 0; u < 2; ++u) {
        int j = u * FT + tid;               // 0..1023 ushort4
        ushort4 h = y4[j];
        sA[SW(2 * j)]     = make_float2(bf2f(h.x), bf2f(h.y));
        sA[SW(2 * j + 1)] = make_float2(bf2f(h.z), bf2f(h.w));
    }
#pragma unroll
    for (int u = 0; u < 4; ++u) {
        int n = 2048 + u * FT + tid;
        sA[SW(n)] = make_float2(0.0f, 0.0f);
    }
    __syncthreads();

    const float scale = 1.0f / 4096.0f;
    for (int st = 0; st < N_STAGES; ++st) {
        fft4096_1g<0>(sA, gW4);                       // forward, in place
        const size_t row = (size_t)st * 1024 + d;
        // untangle -> Y, multiply by F, repack
#pragma unroll
        for (int u = 0; u < 4; ++u) {
            int s = u * FT + tid;
            if (s < 2047) {
                int k = s + 1, nk = 4096 - k;
                float2 w = gW8[k];
                float2 Fk = spec_load(specv, spec_bf16, row, k);
                float2 Fn = spec_load(specv, spec_bf16, row, nk);
                float2 Zk = sA[SW(k)], Zn = sA[SW(nk)];
                float2 Ye = make_float2(0.5f * (Zk.x + Zn.x), 0.5f * (Zk.y - Zn.y));
                float2 Yo = make_float2(0.5f * (Zk.y + Zn.y), -0.5f * (Zk.x - Zn.x));
                float2 wYo = cmul(w, Yo);
                float2 Yk = cadd(Ye, wYo);
                float2 Ynk = conjf2(csub(Ye, wYo));
                float2 Hk = cmul(Yk, Fk);
                float2 Hn = cmul(Ynk, Fn);
                float2 He = make_float2(0.5f * (Hk.x + Hn.x), 0.5f * (Hk.y - Hn.y));
                float2 Hd = make_float2(0.5f * (Hk.x - Hn.x), 0.5f * (Hk.y + Hn.y));
                float2 Ho = cmul(conjf2(w), Hd);
                sA[SW(k)]  = make_float2(He.x - Ho.y, He.y + Ho.x);
                sA[SW(nk)] = make_float2(He.x + Ho.y, Ho.x - He.y);
            }
        }
        if (tid == 0) {
            float2 F0 = spec_load(specv, spec_bf16, row, 0);
            float2 FN = spec_load(specv, spec_bf16, row, 4096);
            float2 F2 = spec_load(specv, spec_bf16, row, 2048);
            float2 Z0 = sA[SW(0)];
            float Y0 = Z0.x + Z0.y, YN = Z0.x - Z0.y;
            float2 H0 = make_float2(Y0 * F0.x, Y0 * F0.y);
            float2 HN = make_float2(YN * FN.x, YN * FN.y);
            float2 He0 = make_float2(0.5f * (H0.x + HN.x), 0.5f * (H0.y + HN.y));
            float2 Ho0 = make_float2(0.5f * (H0.x - HN.x), 0.5f * (H0.y - HN.y));
            sA[SW(0)] = make_float2(He0.x - Ho0.y, He0.y + Ho0.x);
            float2 H2 = cmul(conjf2(sA[SW(2048)]), F2);
            sA[SW(2048)] = conjf2(H2);
        }
        __syncthreads();
        fft4096_1g<1>(sA, gW4);                       // inverse (unnormalized)

        const ushort4* g4 = (const ushort4*)&xpT[((size_t)((st + 1) * 4 + bb) * 1024 + d) * T_LEN];
        if (st < N_STAGES - 1) {
#pragma unroll
            for (int u = 0; u < 2; ++u) {
                int j = u * FT + tid;
                ushort4 h = g4[j];
                float2 v0 = sA[SW(2 * j)], v1 = sA[SW(2 * j + 1)];
                sA[SW(2 * j)]     = make_float2(v0.x * scale * bf2f(h.x), v0.y * scale * bf2f(h.y));
                sA[SW(2 * j + 1)] = make_float2(v1.x * scale * bf2f(h.z), v1.y * scale * bf2f(h.w));
            }
#pragma unroll
            for (int u = 0; u < 4; ++u) {
                int n = 2048 + u * FT + tid;
                sA[SW(n)] = make_float2(0.0f, 0.0f);
            }
            __syncthreads();
        } else {
            ushort4* yrow = (ushort4*)&yT[((size_t)bb * 1024 + d) * T_LEN];
#pragma unroll
            for (int u = 0; u < 2; ++u) {
                int j = u * FT + tid;
                ushort4 h = g4[j];
                float2 v0 = sA[SW(2 * j)], v1 = sA[SW(2 * j + 1)];
                yrow[j] = make_ushort4(f2bf(v0.x * scale * bf2f(h.x)),
                                       f2bf(v0.y * scale * bf2f(h.y)),
                                       f2bf(v1.x * scale * bf2f(h.z)),
                                       f2bf(v1.y * scale * bf2f(h.w)));
            }
        }
    }
}

// ---------------------------------------------------------------- yT (B,D,T) bf16 -> out (B,T,D) f32
__global__ __launch_bounds__(256) void transpose_out(const bf16_t* __restrict__ yT,
                                                     float* __restrict__ out) {
    __shared__ float tile[32][33];
    const int tb = blockIdx.z;
    const int t0 = blockIdx.x * 32;
    const int d0 = blockIdx.y * 32;
    const int tx = threadIdx.x & 31;
    const int ty = threadIdx.x >> 5;
    for (int i = ty; i < 32; i += 8)
        tile[i][tx] = bf2f(yT[((size_t)tb * 1024 + d0 + i) * 4096 + t0 + tx]);
    __syncthreads();
    for (int i = ty; i < 32; i += 8)
        out[((size_t)tb * 4096 + t0 + i) * 1024 + d0 + tx] = tile[tx][i];
}

// ---------------------------------------------------------------- launch
extern "C" void kernel_launch(void* const* d_in, const int* in_sizes, int n_in,
                              void* d_out, int out_size, void* d_ws, size_t ws_size,
                              hipStream_t stream) {
    const float* X   = (const float*)d_in[0];
    const float* Wp  = (const float*)d_in[1];
    const float* bp  = (const float*)d_in[2];
    const float* Wf  = (const float*)d_in[3];
    const float* bfv = (const float*)d_in[4];
    float* out = (float*)d_out;
    char* ws = (char*)d_ws;

    const size_t XPT_BYTES  = (size_t)134217728;
    const size_t SPEC_F32_B = (size_t)3 * 1024 * 4097 * 8;
    const size_t SPEC_BF_B  = (size_t)3 * 1024 * 4097 * 4;
    const size_t XBF_BYTES  = (size_t)33554432;
    const size_t WPT_BYTES  = (size_t)8388608;
    const size_t TW_BYTES   = (size_t)20480;          // gW4 512 + gW8 2048 float2

    bf16_t* xpT   = (bf16_t*)ws;
    bf16_t* posbf = (bf16_t*)ws;
    bf16_t* WfT   = (bf16_t*)(ws + 16777216);
    float*  fT    = (float*)(ws + 33554432);
    void*   spec  = (void*)(ws + XPT_BYTES);

    int spec_bf16;
    size_t spec_bytes;
    if (ws_size >= XPT_BYTES + SPEC_F32_B + XBF_BYTES + WPT_BYTES + TW_BYTES) {
        spec_bf16 = 0; spec_bytes = SPEC_F32_B;
    } else {
        spec_bf16 = 1; spec_bytes = SPEC_BF_B;
    }
    bf16_t* Xbf = (bf16_t*)(ws + XPT_BYTES + spec_bytes);
    bf16_t* WpT = (bf16_t*)(ws + XPT_BYTES + spec_bytes + XBF_BYTES);
    float2* gW4 = (float2*)(ws + XPT_BYTES + spec_bytes + XBF_BYTES + WPT_BYTES);
    float2* gW8 = gW4 + 512;
    bf16_t* yT  = Xbf;   // reuse after GEMM2 consumes Xbf

    // 0. twiddle tables (global, L2-resident)
    twiddle_init_kernel<<<10, 256, 0, stream>>>(gW4, gW8);

    // 1. positional encoding (bf16)
    pos_kernel<<<(T_LEN * D_DIM) / 256, 256, 0, stream>>>(posbf);

    // 2. WfT = transpose(Wf); f = pos @ Wf + bf -> fT f32 [(i*D+d)][t]
    transpose_to_bf16<<<dim3(3072 / 32, 1024 / 32), 256, 0, stream>>>(Wf, WfT, 1024, 3072);
    mfma_gemm<1><<<768, 256, 0, stream>>>(posbf, WfT, bfv, fT, 4096, 3072, 1024, 24);

    // 3. filter spectra (packed real FFT, 32KB LDS, global twiddles)
    filter_fft_kernel<<<N_STAGES * D_DIM, FT, 0, stream>>>(fT, spec, spec_bf16, gW4, gW8);

    // 4. Xbf, WpT ; xp = X @ Wp + bp -> xpT bf16
    f32_to_bf16_kernel<<<8192, 256, 0, stream>>>(X, Xbf, 2097152);
    transpose_to_bf16<<<dim3(4096 / 32, 1024 / 32), 256, 0, stream>>>(Wp, WpT, 1024, 4096);
    mfma_gemm<0><<<4096, 256, 0, stream>>>(Xbf, WpT, bp, xpT, 16384, 4096, 1024, 32);

    // 5. fused 3-stage FFT conv + gating, 1 seq/block (32KB LDS) -> yT
    conv_kernel<<<4 * D_DIM, FT, 0, stream>>>(xpT, spec, spec_bf16, yT, gW4, gW8);

    // 6. transpose to output layout (B,T,D) f32
    transpose_out<<<dim3(4096 / 32, 1024 / 32, B_DIM), 256, 0, stream>>>(yT, out);
}

// Round 18
// 727.430 us; speedup vs baseline: 1.1558x; 1.1558x over previous
//
#include <hip/hip_runtime.h>
#include <math.h>

#define T_LEN 4096
#define D_DIM 1024
#define B_DIM 4
#define N_STAGES 3
#define FT 512          // threads for filter FFT kernel
#define CT 256          // threads for conv kernel (256-thr blocks pack 2-4/CU; 512-thr never did above 64 VGPR)

typedef unsigned short bf16_t;
typedef __bf16 bf16x8 __attribute__((ext_vector_type(8)));
typedef float f32x4 __attribute__((ext_vector_type(4)));

// LDS bank swizzle at float2 granularity — R10/R15-verified conflict floor.
#define SW(i) ((i) ^ ((((unsigned)(i)) >> 4) & 15))

// exp(-i*pi/4) fold constant for untangle twiddles k >= 1024
#define W8R 0.70710678118654752f

// ---------------------------------------------------------------- helpers
__device__ __forceinline__ bf16_t f2bf(float f) {
    union { float f; unsigned u; } v; v.f = f;
    unsigned r = v.u + 0x7FFFu + ((v.u >> 16) & 1u);   // round-nearest-even
    return (bf16_t)(r >> 16);
}
__device__ __forceinline__ float bf2f(bf16_t h) {
    union { unsigned u; float f; } v; v.u = ((unsigned)h) << 16;
    return v.f;
}
__device__ __forceinline__ float2 cmul(float2 a, float2 b) {
    return make_float2(a.x * b.x - a.y * b.y, a.x * b.y + a.y * b.x);
}
__device__ __forceinline__ float2 cadd(float2 a, float2 b) { return make_float2(a.x + b.x, a.y + b.y); }
__device__ __forceinline__ float2 csub(float2 a, float2 b) { return make_float2(a.x - b.x, a.y - b.y); }
__device__ __forceinline__ float2 conjf2(float2 a) { return make_float2(a.x, -a.y); }

#define GLOAD_LDS16(gp, lp) __builtin_amdgcn_global_load_lds( \
    (const __attribute__((address_space(1))) void*)(gp),      \
    (__attribute__((address_space(3))) void*)(lp), 16, 0, 0)

// ---------------------------------------------------------------- pos encoding (bf16 out)
__global__ __launch_bounds__(256) void pos_kernel(bf16_t* __restrict__ posbf) {
    int idx = blockIdx.x * 256 + threadIdx.x;
    int t = idx >> 10;
    int k = idx & 1023;
    float e = (float)(k & ~1) / (float)D_DIM;
    float r = exp2f(-e * 13.287712379549449f);          // 10000^-e
    float angle = (float)t * r;
    float v = (k & 1) ? cosf(angle) : sinf(angle);
    posbf[idx] = f2bf(v);
}

// ---------------------------------------------------------------- f32 -> bf16 copy
__global__ __launch_bounds__(256) void f32_to_bf16_kernel(const float* __restrict__ in,
                                                          bf16_t* __restrict__ out, int n8) {
    int i = blockIdx.x * 256 + threadIdx.x;
    if (i >= n8) return;
    float4 a = ((const float4*)in)[i * 2];
    float4 b = ((const float4*)in)[i * 2 + 1];
    ((ushort4*)out)[i * 2]     = make_ushort4(f2bf(a.x), f2bf(a.y), f2bf(a.z), f2bf(a.w));
    ((ushort4*)out)[i * 2 + 1] = make_ushort4(f2bf(b.x), f2bf(b.y), f2bf(b.z), f2bf(b.w));
}

// ---------------------------------------------------------------- W [K][N] f32 -> WT [N][K] bf16
__global__ __launch_bounds__(256) void transpose_to_bf16(const float* __restrict__ in,
                                                         bf16_t* __restrict__ out, int K, int N) {
    __shared__ float tile[32][33];
    const int n0 = blockIdx.x * 32;
    const int k0 = blockIdx.y * 32;
    const int tx = threadIdx.x & 31;
    const int ty = threadIdx.x >> 5;
    for (int i = ty; i < 32; i += 8)
        tile[i][tx] = in[(size_t)(k0 + i) * N + n0 + tx];
    __syncthreads();
    for (int i = ty; i < 32; i += 8)
        out[(size_t)(n0 + i) * K + k0 + tx] = f2bf(tile[tx][i]);
}

// ---------------------------------------------------------------- bf16 MFMA GEMM (m97 structure)
template <int MODE>
__global__ __launch_bounds__(256) void mfma_gemm(const bf16_t* __restrict__ A,
                                                 const bf16_t* __restrict__ BT,
                                                 const float* __restrict__ bias,
                                                 void* __restrict__ outv,
                                                 int M, int N, int K, int nbx) {
    constexpr int SMEM_BYTES = (MODE == 0) ? (128 * 136 * 2) : (128 * 132 * 4);
    __shared__ __align__(16) char smem[SMEM_BYTES];
    bf16_t* As = (bf16_t*)smem;
    bf16_t* Bs = (bf16_t*)(smem + 8192);

    const int tid = threadIdx.x;
    const int lane = tid & 63;
    const int w = tid >> 6;
    const int wr = w >> 1, wc = w & 1;

    const int nwg = gridDim.x;
    const int q = nwg >> 3;
    const int swz = (blockIdx.x & 7) * q + (blockIdx.x >> 3);
    const int by = swz / nbx, bx = swz - by * nbx;
    const int row0 = by * 128, col0 = bx * 128;

    f32x4 acc[4][4];
#pragma unroll
    for (int m = 0; m < 4; ++m)
#pragma unroll
        for (int n = 0; n < 4; ++n) acc[m][n] = (f32x4)(0.0f);

    int offs[2], rr[2], kk8[2];
#pragma unroll
    for (int c = 0; c < 2; ++c) {
        offs[c] = (w * 2 + c) * 1024 + lane * 16;
        rr[c] = offs[c] >> 6;
        kk8[c] = ((offs[c] >> 4) & 3) * 8;
    }

    for (int k0 = 0; k0 < K; k0 += 32) {
#pragma unroll
        for (int c = 0; c < 2; ++c) {
            const bf16_t* gA = A + (size_t)(row0 + rr[c]) * K + k0 + kk8[c];
            GLOAD_LDS16(gA, As + (w * 2 + c) * 512);
            const bf16_t* gB = BT + (size_t)(col0 + rr[c]) * K + k0 + kk8[c];
            GLOAD_LDS16(gB, Bs + (w * 2 + c) * 512);
        }
        __syncthreads();

        bf16x8 af[4], bfr[4];
#pragma unroll
        for (int m = 0; m < 4; ++m)
            af[m] = *(const bf16x8*)&As[(wr * 64 + m * 16 + (lane & 15)) * 32 + (lane >> 4) * 8];
#pragma unroll
        for (int n = 0; n < 4; ++n)
            bfr[n] = *(const bf16x8*)&Bs[(wc * 64 + n * 16 + (lane & 15)) * 32 + (lane >> 4) * 8];
#pragma unroll
        for (int m = 0; m < 4; ++m)
#pragma unroll
            for (int n = 0; n < 4; ++n)
                acc[m][n] = __builtin_amdgcn_mfma_f32_16x16x32_bf16(af[m], bfr[n], acc[m][n], 0, 0, 0);
        __syncthreads();
    }

    if (MODE == 0) {
        bf16_t* Cs = (bf16_t*)smem;           // [128 cols][pitch 136]
#pragma unroll
        for (int m = 0; m < 4; ++m)
#pragma unroll
            for (int n = 0; n < 4; ++n) {
                int cl = wc * 64 + n * 16 + (lane & 15);
                int rlb = wr * 64 + m * 16 + ((lane >> 4) << 2);
                float bb = bias[col0 + cl];
#pragma unroll
                for (int j = 0; j < 4; ++j)
                    Cs[cl * 136 + rlb + j] = f2bf(acc[m][n][j] + bb);
            }
        __syncthreads();
        int dl = tid >> 1, th = tid & 1;
        int cc = col0 + dl;
        int s = cc >> 10, d = cc & 1023;
        int b = row0 >> 12;
        int t0 = (row0 & 4095) + th * 64;
        uint4* dst = (uint4*)&((bf16_t*)outv)[((size_t)(s * 4 + b) * 1024 + d) * 4096 + t0];
        const uint4* src = (const uint4*)&Cs[dl * 136 + th * 64];
#pragma unroll
        for (int j = 0; j < 8; ++j) dst[j] = src[j];
    } else {
        float* CsF = (float*)smem;            // [128 cols][pitch 132]
#pragma unroll
        for (int m = 0; m < 4; ++m)
#pragma unroll
            for (int n = 0; n < 4; ++n) {
                int cl = wc * 64 + n * 16 + (lane & 15);
                int rlb = wr * 64 + m * 16 + ((lane >> 4) << 2);
                float bb = bias[col0 + cl];
#pragma unroll
                for (int j = 0; j < 4; ++j)
                    CsF[cl * 132 + rlb + j] = acc[m][n][j] + bb;
            }
        __syncthreads();
        int dl = tid >> 1, th = tid & 1;
        int cc = col0 + dl;
        uint4* dst = (uint4*)&((float*)outv)[(size_t)cc * 4096 + row0 + th * 64];
        const uint4* src = (const uint4*)&CsF[dl * 132 + th * 64];
#pragma unroll
        for (int j = 0; j < 16; ++j) dst[j] = src[j];
    }
}

// ---------------------------------------------------------------- radix-8 DFT building blocks
template <int INV>
__device__ __forceinline__ void bfly4(float2& a, float2& b, float2& c, float2& d) {
    float2 t0 = cadd(a, c), t1 = csub(a, c), t2 = cadd(b, d), t3 = csub(b, d);
    float2 it3 = INV ? make_float2(-t3.y, t3.x) : make_float2(t3.y, -t3.x);
    a = cadd(t0, t2); b = cadd(t1, it3); c = csub(t0, t2); d = csub(t1, it3);
}

// in-register DFT-8; on return x[q] = F_q (natural order)
template <int INV>
__device__ __forceinline__ void dft8(float2 (&x)[8]) {
    bfly4<INV>(x[0], x[2], x[4], x[6]);
    bfly4<INV>(x[1], x[3], x[5], x[7]);
    const float s2 = 0.70710678118654752f;
    const float2 o1 = INV ? make_float2(s2, s2) : make_float2(s2, -s2);
    const float2 o3 = INV ? make_float2(-s2, s2) : make_float2(-s2, -s2);
    x[3] = cmul(x[3], o1);
    x[5] = INV ? make_float2(-x[5].y, x[5].x) : make_float2(x[5].y, -x[5].x);
    x[7] = cmul(x[7], o3);
    float2 F0 = cadd(x[0], x[1]), F4 = csub(x[0], x[1]);
    float2 F1 = cadd(x[2], x[3]), F5 = csub(x[2], x[3]);
    float2 F2 = cadd(x[4], x[5]), F6 = csub(x[4], x[5]);
    float2 F3 = cadd(x[6], x[7]), F7 = csub(x[6], x[7]);
    x[0] = F0; x[1] = F1; x[2] = F2; x[3] = F3;
    x[4] = F4; x[5] = F5; x[6] = F6; x[7] = F7;
}

// Wu table: 1024 entries, Wu[k] = exp(-i*pi*k/4096), k in [0,1024).
// Pass twiddle W_4096^jm = Wu[2*jm] (2*jm <= 1022 always).
// Untangle twiddle for k in [1024,2048): Wu[k-1024] * exp(-i*pi/4).
__device__ __forceinline__ float2 untangle_w(const float2* __restrict__ Wu, int k) {
    if (k < 1024) return Wu[k];
    float2 b = Wu[k - 1024];
    return make_float2(W8R * (b.x + b.y), W8R * (b.y - b.x));   // b * (W8R, -W8R)
}

// ---------------------------------------------------------------- single-seq radix-8 pass (filter kernel, 512 thr)
template <int INV, int M>
__device__ __forceinline__ void r8_pass(float2* __restrict__ s, const float2* __restrict__ Wu) {
    const int p = threadIdx.x;
    const int r = p & (M - 1);
    const int jm = p - r;
    float2 x[8];
#pragma unroll
    for (int c = 0; c < 8; ++c) x[c] = s[SW(p + 512 * c)];
    __syncthreads();
    dft8<INV>(x);
    const int base = 8 * jm + r;
    if (M == 512) {
#pragma unroll
        for (int q = 0; q < 8; ++q) s[SW(base + q * 512)] = x[q];
    } else {
        float2 w1 = Wu[2 * jm];
        if (INV) w1.y = -w1.y;
        float2 w2 = cmul(w1, w1);
        float2 w3 = cmul(w2, w1);
        float2 w4 = cmul(w2, w2);
        s[SW(base)]         = x[0];
        s[SW(base + M)]     = cmul(w1, x[1]);
        s[SW(base + 2 * M)] = cmul(w2, x[2]);
        s[SW(base + 3 * M)] = cmul(w3, x[3]);
        s[SW(base + 4 * M)] = cmul(w4, x[4]);
        s[SW(base + 5 * M)] = cmul(cmul(w4, w1), x[5]);
        s[SW(base + 6 * M)] = cmul(cmul(w4, w2), x[6]);
        s[SW(base + 7 * M)] = cmul(cmul(w4, w3), x[7]);
    }
    __syncthreads();
}

template <int INV>
__device__ __forceinline__ void fft4096_ip(float2* __restrict__ s, const float2* __restrict__ Wu) {
    r8_pass<INV, 1>(s, Wu);
    r8_pass<INV, 8>(s, Wu);
    r8_pass<INV, 64>(s, Wu);
    r8_pass<INV, 512>(s, Wu);
}

// ---------------------------------------------------------------- 1-seq pass, 256 thr, 2 butterflies/thread
// Thread owns butterflies {tid, tid+256}. Reads both -> bar -> compute/write
// sequentially (peak live ~60 regs). 2 barriers/pass.
template <int INV, int M>
__device__ __forceinline__ void r8_pass256(float2* __restrict__ s,
                                           const float2* __restrict__ Wu) {
    const int t0 = threadIdx.x;             // 0..255
    float2 x[2][8];
#pragma unroll
    for (int h = 0; h < 2; ++h) {
        const int p = t0 + 256 * h;
#pragma unroll
        for (int c = 0; c < 8; ++c) x[h][c] = s[SW(p + 512 * c)];
    }
    __syncthreads();                        // all reads complete
#pragma unroll
    for (int h = 0; h < 2; ++h) {
        const int p = t0 + 256 * h;
        const int r = p & (M - 1);
        const int jm = p - r;
        const int base = 8 * jm + r;
        dft8<INV>(x[h]);
        if (M == 512) {
#pragma unroll
            for (int q = 0; q < 8; ++q) s[SW(base + q * 512)] = x[h][q];
        } else {
            float2 w1 = Wu[2 * jm];
            if (INV) w1.y = -w1.y;
            float2 w2 = cmul(w1, w1);
            float2 w3 = cmul(w2, w1);
            float2 w4 = cmul(w2, w2);
            s[SW(base)]         = x[h][0];
            s[SW(base + M)]     = cmul(w1, x[h][1]);
            s[SW(base + 2 * M)] = cmul(w2, x[h][2]);
            s[SW(base + 3 * M)] = cmul(w3, x[h][3]);
            s[SW(base + 4 * M)] = cmul(w4, x[h][4]);
            s[SW(base + 5 * M)] = cmul(cmul(w4, w1), x[h][5]);
            s[SW(base + 6 * M)] = cmul(cmul(w4, w2), x[h][6]);
            s[SW(base + 7 * M)] = cmul(cmul(w4, w3), x[h][7]);
        }
    }
    __syncthreads();                        // all writes complete
}

template <int INV>
__device__ __forceinline__ void fft4096_256(float2* __restrict__ s,
                                            const float2* __restrict__ Wu) {
    r8_pass256<INV, 1>(s, Wu);
    r8_pass256<INV, 8>(s, Wu);
    r8_pass256<INV, 64>(s, Wu);
    r8_pass256<INV, 512>(s, Wu);
}

// Wu init: 1024 entries, sincos OUTSIDE loops (proven-safe placement).
template <int NTHR>
__device__ __forceinline__ void init_wu(float2* __restrict__ Wu) {
    const int tid = threadIdx.x;
#pragma unroll
    for (int u = 0; u < (1024 + NTHR - 1) / NTHR; ++u) {
        int k = u * NTHR + tid;
        if (k < 1024) {
            float sn, cs;
            __sincosf((float)k * -7.669903939428206e-4f, &sn, &cs);  // -pi/4096
            Wu[k] = make_float2(cs, sn);
        }
    }
}

// spec accessors (half-spectrum rows of 4097 complex, f32 or bf16 pairs)
__device__ __forceinline__ float2 spec_load(const void* spec, int bf, size_t row, int k) {
    if (bf) {
        ushort2 h = ((const ushort2*)spec)[row * 4097 + k];
        return make_float2(bf2f(h.x), bf2f(h.y));
    }
    return ((const float2*)spec)[row * 4097 + k];
}
__device__ __forceinline__ void spec_store(void* spec, int bf, size_t row, int k, float2 v) {
    if (bf) ((ushort2*)spec)[row * 4097 + k] = make_ushort2(f2bf(v.x), f2bf(v.y));
    else    ((float2*)spec)[row * 4097 + k] = v;
}

// ---------------------------------------------------------------- filter spectra (packed real FFT, R15-proven form)
__global__ __launch_bounds__(FT)
void filter_fft_kernel(const float* __restrict__ fT,
                       void* __restrict__ specv,
                       int spec_bf16) {
    __shared__ __align__(16) float2 sA[4096];
    __shared__ __align__(16) float2 Wu[1024];
    const int tid = threadIdx.x;
    const size_t row = blockIdx.x;          // i*1024 + d
    init_wu<FT>(Wu);
    const float4* f4 = (const float4*)&fT[row * T_LEN];
#pragma unroll
    for (int u = 0; u < 2; ++u) {
        int j = u * FT + tid;               // 0..1023
        float4 v = f4[j];
        sA[SW(2 * j)]     = make_float2(v.x, v.y);
        sA[SW(2 * j + 1)] = make_float2(v.z, v.w);
    }
#pragma unroll
    for (int u = 0; u < 4; ++u) {
        int n = 2048 + u * FT + tid;
        sA[SW(n)] = make_float2(0.0f, 0.0f);
    }
    __syncthreads();
    fft4096_ip<0>(sA, Wu);
    // untangle: F[k] = Ye + W_8192^k * Yo ; F[4096-k] = conj(Ye - W^k Yo)
#pragma unroll
    for (int u = 0; u < 4; ++u) {
        int s = u * FT + tid;
        if (s < 2047) {
            int k = s + 1, nk = 4096 - k;
            float2 Zk = sA[SW(k)], Zn = sA[SW(nk)];
            float2 Ye = make_float2(0.5f * (Zk.x + Zn.x), 0.5f * (Zk.y - Zn.y));
            float2 Yo = make_float2(0.5f * (Zk.y + Zn.y), -0.5f * (Zk.x - Zn.x));
            float2 w = untangle_w(Wu, k);
            float2 wYo = cmul(w, Yo);
            spec_store(specv, spec_bf16, row, k, cadd(Ye, wYo));
            spec_store(specv, spec_bf16, row, nk, conjf2(csub(Ye, wYo)));
        }
    }
    if (tid == 0) {
        float2 Z0 = sA[SW(0)];
        spec_store(specv, spec_bf16, row, 0,    make_float2(Z0.x + Z0.y, 0.0f));
        spec_store(specv, spec_bf16, row, 4096, make_float2(Z0.x - Z0.y, 0.0f));
        spec_store(specv, spec_bf16, row, 2048, conjf2(sA[SW(2048)]));
    }
}

// ---------------------------------------------------------------- fused 3-stage conv, 1 seq/block, 256 thr
// Grid 4096 (d-major: blocks of same d adjacent -> spec rows shared in L2).
// LDS = 32768 + 8192 = 40,960 B -> up to 4 blocks/CU. 256-thr blocks are the
// only size this session observed co-scheduling at VGPR > 64 (R2 GEMM: 33%).
__global__ __launch_bounds__(CT)
void conv_kernel(const bf16_t* __restrict__ xpT,
                 const void* __restrict__ specv,
                 int spec_bf16,
                 bf16_t* __restrict__ yT) {
    __shared__ __align__(16) float2 sA[4096];
    __shared__ __align__(16) float2 Wu[1024];
    const int tid = threadIdx.x;
    const int d  = blockIdx.x >> 2;         // 0..1023
    const int bb = blockIdx.x & 3;          // seq 0..3
    init_wu<CT>(Wu);

    const ushort4* y4 = (const ushort4*)&xpT[((size_t)bb * 1024 + d) * T_LEN];
#pragma unroll
    for (int u = 0; u < 4; ++u) {
        int j = u * CT + tid;               // 0..1023 ushort4
        ushort4 h = y4[j];
        sA[SW(2 * j)]     = make_float2(bf2f(h.x), bf2f(h.y));
        sA[SW(2 * j + 1)] = make_float2(bf2f(h.z), bf2f(h.w));
    }
#pragma unroll
    for (int u = 0; u < 8; ++u) {
        int n = 2048 + u * CT + tid;
        sA[SW(n)] = make_float2(0.0f, 0.0f);
    }
    __syncthreads();

    const float scale = 1.0f / 4096.0f;
    for (int st = 0; st < N_STAGES; ++st) {
        fft4096_256<0>(sA, Wu);                       // forward, in place
        const size_t row = (size_t)st * 1024 + d;
        // untangle -> Y, multiply by F, repack
#pragma unroll
        for (int u = 0; u < 8; ++u) {
            int s = u * CT + tid;
            if (s < 2047) {
                int k = s + 1, nk = 4096 - k;
                float2 w = untangle_w(Wu, k);
                float2 Fk = spec_load(specv, spec_bf16, row, k);
                float2 Fn = spec_load(specv, spec_bf16, row, nk);
                float2 Zk = sA[SW(k)], Zn = sA[SW(nk)];
                float2 Ye = make_float2(0.5f * (Zk.x + Zn.x), 0.5f * (Zk.y - Zn.y));
                float2 Yo = make_float2(0.5f * (Zk.y + Zn.y), -0.5f * (Zk.x - Zn.x));
                float2 wYo = cmul(w, Yo);
                float2 Yk = cadd(Ye, wYo);
                float2 Ynk = conjf2(csub(Ye, wYo));
                float2 Hk = cmul(Yk, Fk);
                float2 Hn = cmul(Ynk, Fn);
                float2 He = make_float2(0.5f * (Hk.x + Hn.x), 0.5f * (Hk.y - Hn.y));
                float2 Hd = make_float2(0.5f * (Hk.x - Hn.x), 0.5f * (Hk.y + Hn.y));
                float2 Ho = cmul(conjf2(w), Hd);
                sA[SW(k)]  = make_float2(He.x - Ho.y, He.y + Ho.x);
                sA[SW(nk)] = make_float2(He.x + Ho.y, Ho.x - He.y);
            }
        }
        if (tid == 0) {
            float2 F0 = spec_load(specv, spec_bf16, row, 0);
            float2 FN = spec_load(specv, spec_bf16, row, 4096);
            float2 F2 = spec_load(specv, spec_bf16, row, 2048);
            float2 Z0 = sA[SW(0)];
            float Y0 = Z0.x + Z0.y, YN = Z0.x - Z0.y;
            float2 H0 = make_float2(Y0 * F0.x, Y0 * F0.y);
            float2 HN = make_float2(YN * FN.x, YN * FN.y);
            float2 He0 = make_float2(0.5f * (H0.x + HN.x), 0.5f * (H0.y + HN.y));
            float2 Ho0 = make_float2(0.5f * (H0.x - HN.x), 0.5f * (H0.y - HN.y));
            sA[SW(0)] = make_float2(He0.x - Ho0.y, He0.y + Ho0.x);
            float2 H2 = cmul(conjf2(sA[SW(2048)]), F2);
            sA[SW(2048)] = conjf2(H2);
        }
        __syncthreads();
        fft4096_256<1>(sA, Wu);                       // inverse (unnormalized)

        const ushort4* g4 = (const ushort4*)&xpT[((size_t)((st + 1) * 4 + bb) * 1024 + d) * T_LEN];
        if (st < N_STAGES - 1) {
#pragma unroll
            for (int u = 0; u < 4; ++u) {
                int j = u * CT + tid;
                ushort4 h = g4[j];
                float2 v0 = sA[SW(2 * j)], v1 = sA[SW(2 * j + 1)];
                sA[SW(2 * j)]     = make_float2(v0.x * scale * bf2f(h.x), v0.y * scale * bf2f(h.y));
                sA[SW(2 * j + 1)] = make_float2(v1.x * scale * bf2f(h.z), v1.y * scale * bf2f(h.w));
            }
#pragma unroll
            for (int u = 0; u < 8; ++u) {
                int n = 2048 + u * CT + tid;
                sA[SW(n)] = make_float2(0.0f, 0.0f);
            }
            __syncthreads();
        } else {
            ushort4* yrow = (ushort4*)&yT[((size_t)bb * 1024 + d) * T_LEN];
#pragma unroll
            for (int u = 0; u < 4; ++u) {
                int j = u * CT + tid;
                ushort4 h = g4[j];
                float2 v0 = sA[SW(2 * j)], v1 = sA[SW(2 * j + 1)];
                yrow[j] = make_ushort4(f2bf(v0.x * scale * bf2f(h.x)),
                                       f2bf(v0.y * scale * bf2f(h.y)),
                                       f2bf(v1.x * scale * bf2f(h.z)),
                                       f2bf(v1.y * scale * bf2f(h.w)));
            }
        }
    }
}

// ---------------------------------------------------------------- yT (B,D,T) bf16 -> out (B,T,D) f32
__global__ __launch_bounds__(256) void transpose_out(const bf16_t* __restrict__ yT,
                                                     float* __restrict__ out) {
    __shared__ float tile[32][33];
    const int tb = blockIdx.z;
    const int t0 = blockIdx.x * 32;
    const int d0 = blockIdx.y * 32;
    const int tx = threadIdx.x & 31;
    const int ty = threadIdx.x >> 5;
    for (int i = ty; i < 32; i += 8)
        tile[i][tx] = bf2f(yT[((size_t)tb * 1024 + d0 + i) * 4096 + t0 + tx]);
    __syncthreads();
    for (int i = ty; i < 32; i += 8)
        out[((size_t)tb * 4096 + t0 + i) * 1024 + d0 + tx] = tile[tx][i];
}

// ---------------------------------------------------------------- launch
extern "C" void kernel_launch(void* const* d_in, const int* in_sizes, int n_in,
                              void* d_out, int out_size, void* d_ws, size_t ws_size,
                              hipStream_t stream) {
    const float* X   = (const float*)d_in[0];
    const float* Wp  = (const float*)d_in[1];
    const float* bp  = (const float*)d_in[2];
    const float* Wf  = (const float*)d_in[3];
    const float* bfv = (const float*)d_in[4];
    float* out = (float*)d_out;
    char* ws = (char*)d_ws;

    const size_t XPT_BYTES  = (size_t)134217728;
    const size_t SPEC_F32_B = (size_t)3 * 1024 * 4097 * 8;
    const size_t SPEC_BF_B  = (size_t)3 * 1024 * 4097 * 4;
    const size_t XBF_BYTES  = (size_t)33554432;
    const size_t WPT_BYTES  = (size_t)8388608;

    bf16_t* xpT   = (bf16_t*)ws;
    bf16_t* posbf = (bf16_t*)ws;
    bf16_t* WfT   = (bf16_t*)(ws + 16777216);
    float*  fT    = (float*)(ws + 33554432);
    void*   spec  = (void*)(ws + XPT_BYTES);

    int spec_bf16;
    size_t spec_bytes;
    if (ws_size >= XPT_BYTES + SPEC_F32_B + XBF_BYTES + WPT_BYTES) {
        spec_bf16 = 0; spec_bytes = SPEC_F32_B;
    } else {
        spec_bf16 = 1; spec_bytes = SPEC_BF_B;
    }
    bf16_t* Xbf = (bf16_t*)(ws + XPT_BYTES + spec_bytes);
    bf16_t* WpT = (bf16_t*)(ws + XPT_BYTES + spec_bytes + XBF_BYTES);
    bf16_t* yT  = Xbf;   // reuse after GEMM2 consumes Xbf

    // 1. positional encoding (bf16)
    pos_kernel<<<(T_LEN * D_DIM) / 256, 256, 0, stream>>>(posbf);

    // 2. WfT = transpose(Wf); f = pos @ Wf + bf -> fT f32 [(i*D+d)][t]
    transpose_to_bf16<<<dim3(3072 / 32, 1024 / 32), 256, 0, stream>>>(Wf, WfT, 1024, 3072);
    mfma_gemm<1><<<768, 256, 0, stream>>>(posbf, WfT, bfv, fT, 4096, 3072, 1024, 24);

    // 3. filter spectra (packed real FFT, radix-8 in-place, R15 form)
    filter_fft_kernel<<<N_STAGES * D_DIM, FT, 0, stream>>>(fT, spec, spec_bf16);

    // 4. Xbf, WpT ; xp = X @ Wp + bp -> xpT bf16
    f32_to_bf16_kernel<<<8192, 256, 0, stream>>>(X, Xbf, 2097152);
    transpose_to_bf16<<<dim3(4096 / 32, 1024 / 32), 256, 0, stream>>>(Wp, WpT, 1024, 4096);
    mfma_gemm<0><<<4096, 256, 0, stream>>>(Xbf, WpT, bp, xpT, 16384, 4096, 1024, 32);

    // 5. fused 3-stage FFT conv + gating, 1 seq/block, 256 thr -> yT
    conv_kernel<<<4 * D_DIM, CT, 0, stream>>>(xpT, spec, spec_bf16, yT);

    // 6. transpose to output layout (B,T,D) f32
    transpose_out<<<dim3(4096 / 32, 1024 / 32, B_DIM), 256, 0, stream>>>(yT, out);
}

// Round 19
// 706.904 us; speedup vs baseline: 1.1893x; 1.0290x over previous
//
#include <hip/hip_runtime.h>
#include <math.h>

#define T_LEN 4096
#define D_DIM 1024
#define B_DIM 4
#define N_STAGES 3
#define FT 512          // threads for filter FFT kernel
#define CT 256          // threads for conv kernel

typedef unsigned short bf16_t;
typedef __bf16 bf16x8 __attribute__((ext_vector_type(8)));
typedef float f32x4 __attribute__((ext_vector_type(4)));

// LDS bank swizzle at float2 granularity — R10/R15-verified conflict floor.
#define SW(i) ((i) ^ ((((unsigned)(i)) >> 4) & 15))

// exp(-i*pi/4) fold constant for untangle twiddles k >= 1024
#define W8R 0.70710678118654752f

// ---------------------------------------------------------------- helpers
__device__ __forceinline__ bf16_t f2bf(float f) {
    union { float f; unsigned u; } v; v.f = f;
    unsigned r = v.u + 0x7FFFu + ((v.u >> 16) & 1u);   // round-nearest-even
    return (bf16_t)(r >> 16);
}
__device__ __forceinline__ float bf2f(bf16_t h) {
    union { unsigned u; float f; } v; v.u = ((unsigned)h) << 16;
    return v.f;
}
__device__ __forceinline__ float2 cmul(float2 a, float2 b) {
    return make_float2(a.x * b.x - a.y * b.y, a.x * b.y + a.y * b.x);
}
__device__ __forceinline__ float2 cadd(float2 a, float2 b) { return make_float2(a.x + b.x, a.y + b.y); }
__device__ __forceinline__ float2 csub(float2 a, float2 b) { return make_float2(a.x - b.x, a.y - b.y); }
__device__ __forceinline__ float2 conjf2(float2 a) { return make_float2(a.x, -a.y); }

#define GLOAD_LDS16(gp, lp) __builtin_amdgcn_global_load_lds( \
    (const __attribute__((address_space(1))) void*)(gp),      \
    (__attribute__((address_space(3))) void*)(lp), 16, 0, 0)

// ---------------------------------------------------------------- pos encoding (bf16 out)
__global__ __launch_bounds__(256) void pos_kernel(bf16_t* __restrict__ posbf) {
    int idx = blockIdx.x * 256 + threadIdx.x;
    int t = idx >> 10;
    int k = idx & 1023;
    float e = (float)(k & ~1) / (float)D_DIM;
    float r = exp2f(-e * 13.287712379549449f);          // 10000^-e
    float angle = (float)t * r;
    float v = (k & 1) ? cosf(angle) : sinf(angle);
    posbf[idx] = f2bf(v);
}

// ---------------------------------------------------------------- f32 -> bf16 copy
__global__ __launch_bounds__(256) void f32_to_bf16_kernel(const float* __restrict__ in,
                                                          bf16_t* __restrict__ out, int n8) {
    int i = blockIdx.x * 256 + threadIdx.x;
    if (i >= n8) return;
    float4 a = ((const float4*)in)[i * 2];
    float4 b = ((const float4*)in)[i * 2 + 1];
    ((ushort4*)out)[i * 2]     = make_ushort4(f2bf(a.x), f2bf(a.y), f2bf(a.z), f2bf(a.w));
    ((ushort4*)out)[i * 2 + 1] = make_ushort4(f2bf(b.x), f2bf(b.y), f2bf(b.z), f2bf(b.w));
}

// ---------------------------------------------------------------- W [K][N] f32 -> WT [N][K] bf16
__global__ __launch_bounds__(256) void transpose_to_bf16(const float* __restrict__ in,
                                                         bf16_t* __restrict__ out, int K, int N) {
    __shared__ float tile[32][33];
    const int n0 = blockIdx.x * 32;
    const int k0 = blockIdx.y * 32;
    const int tx = threadIdx.x & 31;
    const int ty = threadIdx.x >> 5;
    for (int i = ty; i < 32; i += 8)
        tile[i][tx] = in[(size_t)(k0 + i) * N + n0 + tx];
    __syncthreads();
    for (int i = ty; i < 32; i += 8)
        out[(size_t)(n0 + i) * K + k0 + tx] = f2bf(tile[tx][i]);
}

// ---------------------------------------------------------------- bf16 MFMA GEMM (m97 structure)
template <int MODE>
__global__ __launch_bounds__(256) void mfma_gemm(const bf16_t* __restrict__ A,
                                                 const bf16_t* __restrict__ BT,
                                                 const float* __restrict__ bias,
                                                 void* __restrict__ outv,
                                                 int M, int N, int K, int nbx) {
    constexpr int SMEM_BYTES = (MODE == 0) ? (128 * 136 * 2) : (128 * 132 * 4);
    __shared__ __align__(16) char smem[SMEM_BYTES];
    bf16_t* As = (bf16_t*)smem;
    bf16_t* Bs = (bf16_t*)(smem + 8192);

    const int tid = threadIdx.x;
    const int lane = tid & 63;
    const int w = tid >> 6;
    const int wr = w >> 1, wc = w & 1;

    const int nwg = gridDim.x;
    const int q = nwg >> 3;
    const int swz = (blockIdx.x & 7) * q + (blockIdx.x >> 3);
    const int by = swz / nbx, bx = swz - by * nbx;
    const int row0 = by * 128, col0 = bx * 128;

    f32x4 acc[4][4];
#pragma unroll
    for (int m = 0; m < 4; ++m)
#pragma unroll
        for (int n = 0; n < 4; ++n) acc[m][n] = (f32x4)(0.0f);

    int offs[2], rr[2], kk8[2];
#pragma unroll
    for (int c = 0; c < 2; ++c) {
        offs[c] = (w * 2 + c) * 1024 + lane * 16;
        rr[c] = offs[c] >> 6;
        kk8[c] = ((offs[c] >> 4) & 3) * 8;
    }

    for (int k0 = 0; k0 < K; k0 += 32) {
#pragma unroll
        for (int c = 0; c < 2; ++c) {
            const bf16_t* gA = A + (size_t)(row0 + rr[c]) * K + k0 + kk8[c];
            GLOAD_LDS16(gA, As + (w * 2 + c) * 512);
            const bf16_t* gB = BT + (size_t)(col0 + rr[c]) * K + k0 + kk8[c];
            GLOAD_LDS16(gB, Bs + (w * 2 + c) * 512);
        }
        __syncthreads();

        bf16x8 af[4], bfr[4];
#pragma unroll
        for (int m = 0; m < 4; ++m)
            af[m] = *(const bf16x8*)&As[(wr * 64 + m * 16 + (lane & 15)) * 32 + (lane >> 4) * 8];
#pragma unroll
        for (int n = 0; n < 4; ++n)
            bfr[n] = *(const bf16x8*)&Bs[(wc * 64 + n * 16 + (lane & 15)) * 32 + (lane >> 4) * 8];
#pragma unroll
        for (int m = 0; m < 4; ++m)
#pragma unroll
            for (int n = 0; n < 4; ++n)
                acc[m][n] = __builtin_amdgcn_mfma_f32_16x16x32_bf16(af[m], bfr[n], acc[m][n], 0, 0, 0);
        __syncthreads();
    }

    if (MODE == 0) {
        bf16_t* Cs = (bf16_t*)smem;           // [128 cols][pitch 136]
#pragma unroll
        for (int m = 0; m < 4; ++m)
#pragma unroll
            for (int n = 0; n < 4; ++n) {
                int cl = wc * 64 + n * 16 + (lane & 15);
                int rlb = wr * 64 + m * 16 + ((lane >> 4) << 2);
                float bb = bias[col0 + cl];
#pragma unroll
                for (int j = 0; j < 4; ++j)
                    Cs[cl * 136 + rlb + j] = f2bf(acc[m][n][j] + bb);
            }
        __syncthreads();
        int dl = tid >> 1, th = tid & 1;
        int cc = col0 + dl;
        int s = cc >> 10, d = cc & 1023;
        int b = row0 >> 12;
        int t0 = (row0 & 4095) + th * 64;
        uint4* dst = (uint4*)&((bf16_t*)outv)[((size_t)(s * 4 + b) * 1024 + d) * 4096 + t0];
        const uint4* src = (const uint4*)&Cs[dl * 136 + th * 64];
#pragma unroll
        for (int j = 0; j < 8; ++j) dst[j] = src[j];
    } else {
        float* CsF = (float*)smem;            // [128 cols][pitch 132]
#pragma unroll
        for (int m = 0; m < 4; ++m)
#pragma unroll
            for (int n = 0; n < 4; ++n) {
                int cl = wc * 64 + n * 16 + (lane & 15);
                int rlb = wr * 64 + m * 16 + ((lane >> 4) << 2);
                float bb = bias[col0 + cl];
#pragma unroll
                for (int j = 0; j < 4; ++j)
                    CsF[cl * 132 + rlb + j] = acc[m][n][j] + bb;
            }
        __syncthreads();
        int dl = tid >> 1, th = tid & 1;
        int cc = col0 + dl;
        uint4* dst = (uint4*)&((float*)outv)[(size_t)cc * 4096 + row0 + th * 64];
        const uint4* src = (const uint4*)&CsF[dl * 132 + th * 64];
#pragma unroll
        for (int j = 0; j < 16; ++j) dst[j] = src[j];
    }
}

// ---------------------------------------------------------------- radix DFT building blocks
template <int INV>
__device__ __forceinline__ void bfly4(float2& a, float2& b, float2& c, float2& d) {
    float2 t0 = cadd(a, c), t1 = csub(a, c), t2 = cadd(b, d), t3 = csub(b, d);
    float2 it3 = INV ? make_float2(-t3.y, t3.x) : make_float2(t3.y, -t3.x);
    a = cadd(t0, t2); b = cadd(t1, it3); c = csub(t0, t2); d = csub(t1, it3);
}

// in-register DFT-8; on return x[q] = F_q (natural order)
template <int INV>
__device__ __forceinline__ void dft8(float2 (&x)[8]) {
    bfly4<INV>(x[0], x[2], x[4], x[6]);
    bfly4<INV>(x[1], x[3], x[5], x[7]);
    const float s2 = 0.70710678118654752f;
    const float2 o1 = INV ? make_float2(s2, s2) : make_float2(s2, -s2);
    const float2 o3 = INV ? make_float2(-s2, s2) : make_float2(-s2, -s2);
    x[3] = cmul(x[3], o1);
    x[5] = INV ? make_float2(-x[5].y, x[5].x) : make_float2(x[5].y, -x[5].x);
    x[7] = cmul(x[7], o3);
    float2 F0 = cadd(x[0], x[1]), F4 = csub(x[0], x[1]);
    float2 F1 = cadd(x[2], x[3]), F5 = csub(x[2], x[3]);
    float2 F2 = cadd(x[4], x[5]), F6 = csub(x[4], x[5]);
    float2 F3 = cadd(x[6], x[7]), F7 = csub(x[6], x[7]);
    x[0] = F0; x[1] = F1; x[2] = F2; x[3] = F3;
    x[4] = F4; x[5] = F5; x[6] = F6; x[7] = F7;
}

// in-register DFT-16 (R5-verified); on return F[q] sits at x[4*(q&3) + (q>>2)].
template <int INV>
__device__ __forceinline__ void dft16(float2 (&x)[16]) {
#pragma unroll
    for (int c1 = 0; c1 < 4; ++c1) bfly4<INV>(x[c1], x[c1 + 4], x[c1 + 8], x[c1 + 12]);
    const float C1 = 0.9238795325112867f, S1 = 0.3826834323650898f, R2 = 0.7071067811865476f;
    const float sg = INV ? 1.0f : -1.0f;
    const float2 w1 = make_float2(C1, sg * S1);
    const float2 w2 = make_float2(R2, sg * R2);
    const float2 w3 = make_float2(S1, sg * C1);
    const float2 w6 = make_float2(-R2, sg * R2);
    const float2 w9 = make_float2(-C1, -sg * S1);
    x[5]  = cmul(x[5], w1);
    x[9]  = cmul(x[9], w2);
    x[13] = cmul(x[13], w3);
    x[6]  = cmul(x[6], w2);
    x[10] = INV ? make_float2(-x[10].y, x[10].x) : make_float2(x[10].y, -x[10].x);  // *w16^4
    x[14] = cmul(x[14], w6);
    x[7]  = cmul(x[7], w3);
    x[11] = cmul(x[11], w6);
    x[15] = cmul(x[15], w9);
#pragma unroll
    for (int q1 = 0; q1 < 4; ++q1) bfly4<INV>(x[4 * q1], x[4 * q1 + 1], x[4 * q1 + 2], x[4 * q1 + 3]);
}

// Wu table: 1024 entries, Wu[k] = exp(-i*pi*k/4096), k in [0,1024).
// Pass twiddle W_4096^j = Wu[2*j] (j < 512 for all uses).
// Untangle twiddle for k in [1024,2048): Wu[k-1024] * exp(-i*pi/4).
__device__ __forceinline__ float2 untangle_w(const float2* __restrict__ Wu, int k) {
    if (k < 1024) return Wu[k];
    float2 b = Wu[k - 1024];
    return make_float2(W8R * (b.x + b.y), W8R * (b.y - b.x));   // b * (W8R, -W8R)
}

// ---------------------------------------------------------------- single-seq radix-8 pass (filter kernel, 512 thr)
template <int INV, int M>
__device__ __forceinline__ void r8_pass(float2* __restrict__ s, const float2* __restrict__ Wu) {
    const int p = threadIdx.x;
    const int r = p & (M - 1);
    const int jm = p - r;
    float2 x[8];
#pragma unroll
    for (int c = 0; c < 8; ++c) x[c] = s[SW(p + 512 * c)];
    __syncthreads();
    dft8<INV>(x);
    const int base = 8 * jm + r;
    if (M == 512) {
#pragma unroll
        for (int q = 0; q < 8; ++q) s[SW(base + q * 512)] = x[q];
    } else {
        float2 w1 = Wu[2 * jm];
        if (INV) w1.y = -w1.y;
        float2 w2 = cmul(w1, w1);
        float2 w3 = cmul(w2, w1);
        float2 w4 = cmul(w2, w2);
        s[SW(base)]         = x[0];
        s[SW(base + M)]     = cmul(w1, x[1]);
        s[SW(base + 2 * M)] = cmul(w2, x[2]);
        s[SW(base + 3 * M)] = cmul(w3, x[3]);
        s[SW(base + 4 * M)] = cmul(w4, x[4]);
        s[SW(base + 5 * M)] = cmul(cmul(w4, w1), x[5]);
        s[SW(base + 6 * M)] = cmul(cmul(w4, w2), x[6]);
        s[SW(base + 7 * M)] = cmul(cmul(w4, w3), x[7]);
    }
    __syncthreads();
}

template <int INV>
__device__ __forceinline__ void fft4096_ip(float2* __restrict__ s, const float2* __restrict__ Wu) {
    r8_pass<INV, 1>(s, Wu);
    r8_pass<INV, 8>(s, Wu);
    r8_pass<INV, 64>(s, Wu);
    r8_pass<INV, 512>(s, Wu);
}

// ---------------------------------------------------------------- radix-16 pass, 256 thr, 1 butterfly/thread
// 4096 = 16^3: 3 passes (M = 1, 16, 256) vs radix-8's 4 — LDS traffic and
// barriers both -25%. dft16 + pass indexing are R5-correctness-verified; the
// R5 perf failure (240 VGPR) was its 15-deep SERIAL sincos chain — replaced
// here by Wu-table base + tree powers interleaved with stores (live ~7 w's).
template <int INV, int M>
__device__ __forceinline__ void r16_pass(float2* __restrict__ s, const float2* __restrict__ Wu) {
    const int p = threadIdx.x;              // 0..255 (4096/16 butterflies)
    const int r = p & (M - 1);
    const int jm = p - r;
    float2 x[16];
#pragma unroll
    for (int c = 0; c < 16; ++c) x[c] = s[SW(p + 256 * c)];
    __syncthreads();
    dft16<INV>(x);
    const int base = 16 * jm + r;
    if (M == 256) {                          // jm == 0: no twiddles
#pragma unroll
        for (int q = 0; q < 16; ++q) s[SW(base + q * 256)] = x[4 * (q & 3) + (q >> 2)];
    } else {
        float2 w1 = Wu[2 * jm];              // W_4096^jm, 2*jm <= 510 in-table
        if (INV) w1.y = -w1.y;
        float2 w2 = cmul(w1, w1);
        float2 w3 = cmul(w2, w1);
        float2 w4 = cmul(w2, w2);
        s[SW(base)]          = x[0];
        s[SW(base + M)]      = cmul(w1, x[4]);
        s[SW(base + 2 * M)]  = cmul(w2, x[8]);
        s[SW(base + 3 * M)]  = cmul(w3, x[12]);
        s[SW(base + 4 * M)]  = cmul(w4, x[1]);
        s[SW(base + 5 * M)]  = cmul(cmul(w4, w1), x[5]);
        s[SW(base + 6 * M)]  = cmul(cmul(w4, w2), x[9]);
        s[SW(base + 7 * M)]  = cmul(cmul(w4, w3), x[13]);
        float2 w8 = cmul(w4, w4);
        s[SW(base + 8 * M)]  = cmul(w8, x[2]);
        s[SW(base + 9 * M)]  = cmul(cmul(w8, w1), x[6]);
        s[SW(base + 10 * M)] = cmul(cmul(w8, w2), x[10]);
        s[SW(base + 11 * M)] = cmul(cmul(w8, w3), x[14]);
        float2 w12 = cmul(w8, w4);
        s[SW(base + 12 * M)] = cmul(w12, x[3]);
        s[SW(base + 13 * M)] = cmul(cmul(w12, w1), x[7]);
        s[SW(base + 14 * M)] = cmul(cmul(w12, w2), x[11]);
        s[SW(base + 15 * M)] = cmul(cmul(w12, w3), x[15]);
    }
    __syncthreads();
}

template <int INV>
__device__ __forceinline__ void fft4096_r16(float2* __restrict__ s, const float2* __restrict__ Wu) {
    r16_pass<INV, 1>(s, Wu);
    r16_pass<INV, 16>(s, Wu);
    r16_pass<INV, 256>(s, Wu);
}

// Wu init: 1024 entries, sincos OUTSIDE loops (proven-safe placement).
template <int NTHR>
__device__ __forceinline__ void init_wu(float2* __restrict__ Wu) {
    const int tid = threadIdx.x;
#pragma unroll
    for (int u = 0; u < (1024 + NTHR - 1) / NTHR; ++u) {
        int k = u * NTHR + tid;
        if (k < 1024) {
            float sn, cs;
            __sincosf((float)k * -7.669903939428206e-4f, &sn, &cs);  // -pi/4096
            Wu[k] = make_float2(cs, sn);
        }
    }
}

// spec accessors (half-spectrum rows of 4097 complex, f32 or bf16 pairs)
__device__ __forceinline__ float2 spec_load(const void* spec, int bf, size_t row, int k) {
    if (bf) {
        ushort2 h = ((const ushort2*)spec)[row * 4097 + k];
        return make_float2(bf2f(h.x), bf2f(h.y));
    }
    return ((const float2*)spec)[row * 4097 + k];
}
__device__ __forceinline__ void spec_store(void* spec, int bf, size_t row, int k, float2 v) {
    if (bf) ((ushort2*)spec)[row * 4097 + k] = make_ushort2(f2bf(v.x), f2bf(v.y));
    else    ((float2*)spec)[row * 4097 + k] = v;
}

// ---------------------------------------------------------------- filter spectra (packed real FFT, R15-proven form)
__global__ __launch_bounds__(FT)
void filter_fft_kernel(const float* __restrict__ fT,
                       void* __restrict__ specv,
                       int spec_bf16) {
    __shared__ __align__(16) float2 sA[4096];
    __shared__ __align__(16) float2 Wu[1024];
    const int tid = threadIdx.x;
    const size_t row = blockIdx.x;          // i*1024 + d
    init_wu<FT>(Wu);
    const float4* f4 = (const float4*)&fT[row * T_LEN];
#pragma unroll
    for (int u = 0; u < 2; ++u) {
        int j = u * FT + tid;               // 0..1023
        float4 v = f4[j];
        sA[SW(2 * j)]     = make_float2(v.x, v.y);
        sA[SW(2 * j + 1)] = make_float2(v.z, v.w);
    }
#pragma unroll
    for (int u = 0; u < 4; ++u) {
        int n = 2048 + u * FT + tid;
        sA[SW(n)] = make_float2(0.0f, 0.0f);
    }
    __syncthreads();
    fft4096_ip<0>(sA, Wu);
    // untangle: F[k] = Ye + W_8192^k * Yo ; F[4096-k] = conj(Ye - W^k Yo)
#pragma unroll
    for (int u = 0; u < 4; ++u) {
        int s = u * FT + tid;
        if (s < 2047) {
            int k = s + 1, nk = 4096 - k;
            float2 Zk = sA[SW(k)], Zn = sA[SW(nk)];
            float2 Ye = make_float2(0.5f * (Zk.x + Zn.x), 0.5f * (Zk.y - Zn.y));
            float2 Yo = make_float2(0.5f * (Zk.y + Zn.y), -0.5f * (Zk.x - Zn.x));
            float2 w = untangle_w(Wu, k);
            float2 wYo = cmul(w, Yo);
            spec_store(specv, spec_bf16, row, k, cadd(Ye, wYo));
            spec_store(specv, spec_bf16, row, nk, conjf2(csub(Ye, wYo)));
        }
    }
    if (tid == 0) {
        float2 Z0 = sA[SW(0)];
        spec_store(specv, spec_bf16, row, 0,    make_float2(Z0.x + Z0.y, 0.0f));
        spec_store(specv, spec_bf16, row, 4096, make_float2(Z0.x - Z0.y, 0.0f));
        spec_store(specv, spec_bf16, row, 2048, conjf2(sA[SW(2048)]));
    }
}

// ---------------------------------------------------------------- fused 3-stage conv, 1 seq/block, 256 thr, radix-16
// Grid 4096 (d-major: blocks of same d adjacent -> spec rows shared in L2).
// LDS = 32768 + 8192 = 40,960 B.
__global__ __launch_bounds__(CT)
void conv_kernel(const bf16_t* __restrict__ xpT,
                 const void* __restrict__ specv,
                 int spec_bf16,
                 bf16_t* __restrict__ yT) {
    __shared__ __align__(16) float2 sA[4096];
    __shared__ __align__(16) float2 Wu[1024];
    const int tid = threadIdx.x;
    const int d  = blockIdx.x >> 2;         // 0..1023
    const int bb = blockIdx.x & 3;          // seq 0..3
    init_wu<CT>(Wu);

    const ushort4* y4 = (const ushort4*)&xpT[((size_t)bb * 1024 + d) * T_LEN];
#pragma unroll
    for (int u = 0; u < 4; ++u) {
        int j = u * CT + tid;               // 0..1023 ushort4
        ushort4 h = y4[j];
        sA[SW(2 * j)]     = make_float2(bf2f(h.x), bf2f(h.y));
        sA[SW(2 * j + 1)] = make_float2(bf2f(h.z), bf2f(h.w));
    }
#pragma unroll
    for (int u = 0; u < 8; ++u) {
        int n = 2048 + u * CT + tid;
        sA[SW(n)] = make_float2(0.0f, 0.0f);
    }
    __syncthreads();

    const float scale = 1.0f / 4096.0f;
    for (int st = 0; st < N_STAGES; ++st) {
        fft4096_r16<0>(sA, Wu);                       // forward, 3 passes
        const size_t row = (size_t)st * 1024 + d;
        // untangle -> Y, multiply by F, repack
#pragma unroll
        for (int u = 0; u < 8; ++u) {
            int s = u * CT + tid;
            if (s < 2047) {
                int k = s + 1, nk = 4096 - k;
                float2 w = untangle_w(Wu, k);
                float2 Fk = spec_load(specv, spec_bf16, row, k);
                float2 Fn = spec_load(specv, spec_bf16, row, nk);
                float2 Zk = sA[SW(k)], Zn = sA[SW(nk)];
                float2 Ye = make_float2(0.5f * (Zk.x + Zn.x), 0.5f * (Zk.y - Zn.y));
                float2 Yo = make_float2(0.5f * (Zk.y + Zn.y), -0.5f * (Zk.x - Zn.x));
                float2 wYo = cmul(w, Yo);
                float2 Yk = cadd(Ye, wYo);
                float2 Ynk = conjf2(csub(Ye, wYo));
                float2 Hk = cmul(Yk, Fk);
                float2 Hn = cmul(Ynk, Fn);
                float2 He = make_float2(0.5f * (Hk.x + Hn.x), 0.5f * (Hk.y - Hn.y));
                float2 Hd = make_float2(0.5f * (Hk.x - Hn.x), 0.5f * (Hk.y + Hn.y));
                float2 Ho = cmul(conjf2(w), Hd);
                sA[SW(k)]  = make_float2(He.x - Ho.y, He.y + Ho.x);
                sA[SW(nk)] = make_float2(He.x + Ho.y, Ho.x - He.y);
            }
        }
        if (tid == 0) {
            float2 F0 = spec_load(specv, spec_bf16, row, 0);
            float2 FN = spec_load(specv, spec_bf16, row, 4096);
            float2 F2 = spec_load(specv, spec_bf16, row, 2048);
            float2 Z0 = sA[SW(0)];
            float Y0 = Z0.x + Z0.y, YN = Z0.x - Z0.y;
            float2 H0 = make_float2(Y0 * F0.x, Y0 * F0.y);
            float2 HN = make_float2(YN * FN.x, YN * FN.y);
            float2 He0 = make_float2(0.5f * (H0.x + HN.x), 0.5f * (H0.y + HN.y));
            float2 Ho0 = make_float2(0.5f * (H0.x - HN.x), 0.5f * (H0.y - HN.y));
            sA[SW(0)] = make_float2(He0.x - Ho0.y, He0.y + Ho0.x);
            float2 H2 = cmul(conjf2(sA[SW(2048)]), F2);
            sA[SW(2048)] = conjf2(H2);
        }
        __syncthreads();
        fft4096_r16<1>(sA, Wu);                       // inverse (unnormalized)

        const ushort4* g4 = (const ushort4*)&xpT[((size_t)((st + 1) * 4 + bb) * 1024 + d) * T_LEN];
        if (st < N_STAGES - 1) {
#pragma unroll
            for (int u = 0; u < 4; ++u) {
                int j = u * CT + tid;
                ushort4 h = g4[j];
                float2 v0 = sA[SW(2 * j)], v1 = sA[SW(2 * j + 1)];
                sA[SW(2 * j)]     = make_float2(v0.x * scale * bf2f(h.x), v0.y * scale * bf2f(h.y));
                sA[SW(2 * j + 1)] = make_float2(v1.x * scale * bf2f(h.z), v1.y * scale * bf2f(h.w));
            }
#pragma unroll
            for (int u = 0; u < 8; ++u) {
                int n = 2048 + u * CT + tid;
                sA[SW(n)] = make_float2(0.0f, 0.0f);
            }
            __syncthreads();
        } else {
            ushort4* yrow = (ushort4*)&yT[((size_t)bb * 1024 + d) * T_LEN];
#pragma unroll
            for (int u = 0; u < 4; ++u) {
                int j = u * CT + tid;
                ushort4 h = g4[j];
                float2 v0 = sA[SW(2 * j)], v1 = sA[SW(2 * j + 1)];
                yrow[j] = make_ushort4(f2bf(v0.x * scale * bf2f(h.x)),
                                       f2bf(v0.y * scale * bf2f(h.y)),
                                       f2bf(v1.x * scale * bf2f(h.z)),
                                       f2bf(v1.y * scale * bf2f(h.w)));
            }
        }
    }
}

// ---------------------------------------------------------------- yT (B,D,T) bf16 -> out (B,T,D) f32
__global__ __launch_bounds__(256) void transpose_out(const bf16_t* __restrict__ yT,
                                                     float* __restrict__ out) {
    __shared__ float tile[32][33];
    const int tb = blockIdx.z;
    const int t0 = blockIdx.x * 32;
    const int d0 = blockIdx.y * 32;
    const int tx = threadIdx.x & 31;
    const int ty = threadIdx.x >> 5;
    for (int i = ty; i < 32; i += 8)
        tile[i][tx] = bf2f(yT[((size_t)tb * 1024 + d0 + i) * 4096 + t0 + tx]);
    __syncthreads();
    for (int i = ty; i < 32; i += 8)
        out[((size_t)tb * 4096 + t0 + i) * 1024 + d0 + tx] = tile[tx][i];
}

// ---------------------------------------------------------------- launch
extern "C" void kernel_launch(void* const* d_in, const int* in_sizes, int n_in,
                              void* d_out, int out_size, void* d_ws, size_t ws_size,
                              hipStream_t stream) {
    const float* X   = (const float*)d_in[0];
    const float* Wp  = (const float*)d_in[1];
    const float* bp  = (const float*)d_in[2];
    const float* Wf  = (const float*)d_in[3];
    const float* bfv = (const float*)d_in[4];
    float* out = (float*)d_out;
    char* ws = (char*)d_ws;

    const size_t XPT_BYTES  = (size_t)134217728;
    const size_t SPEC_F32_B = (size_t)3 * 1024 * 4097 * 8;
    const size_t SPEC_BF_B  = (size_t)3 * 1024 * 4097 * 4;
    const size_t XBF_BYTES  = (size_t)33554432;
    const size_t WPT_BYTES  = (size_t)8388608;

    bf16_t* xpT   = (bf16_t*)ws;
    bf16_t* posbf = (bf16_t*)ws;
    bf16_t* WfT   = (bf16_t*)(ws + 16777216);
    float*  fT    = (float*)(ws + 33554432);
    void*   spec  = (void*)(ws + XPT_BYTES);

    int spec_bf16;
    size_t spec_bytes;
    if (ws_size >= XPT_BYTES + SPEC_F32_B + XBF_BYTES + WPT_BYTES) {
        spec_bf16 = 0; spec_bytes = SPEC_F32_B;
    } else {
        spec_bf16 = 1; spec_bytes = SPEC_BF_B;
    }
    bf16_t* Xbf = (bf16_t*)(ws + XPT_BYTES + spec_bytes);
    bf16_t* WpT = (bf16_t*)(ws + XPT_BYTES + spec_bytes + XBF_BYTES);
    bf16_t* yT  = Xbf;   // reuse after GEMM2 consumes Xbf

    // 1. positional encoding (bf16)
    pos_kernel<<<(T_LEN * D_DIM) / 256, 256, 0, stream>>>(posbf);

    // 2. WfT = transpose(Wf); f = pos @ Wf + bf -> fT f32 [(i*D+d)][t]
    transpose_to_bf16<<<dim3(3072 / 32, 1024 / 32), 256, 0, stream>>>(Wf, WfT, 1024, 3072);
    mfma_gemm<1><<<768, 256, 0, stream>>>(posbf, WfT, bfv, fT, 4096, 3072, 1024, 24);

    // 3. filter spectra (packed real FFT, radix-8, R15 form)
    filter_fft_kernel<<<N_STAGES * D_DIM, FT, 0, stream>>>(fT, spec, spec_bf16);

    // 4. Xbf, WpT ; xp = X @ Wp + bp -> xpT bf16
    f32_to_bf16_kernel<<<8192, 256, 0, stream>>>(X, Xbf, 2097152);
    transpose_to_bf16<<<dim3(4096 / 32, 1024 / 32), 256, 0, stream>>>(Wp, WpT, 1024, 4096);
    mfma_gemm<0><<<4096, 256, 0, stream>>>(Xbf, WpT, bp, xpT, 16384, 4096, 1024, 32);

    // 5. fused 3-stage FFT conv + gating, 1 seq/block, 256 thr, radix-16 -> yT
    conv_kernel<<<4 * D_DIM, CT, 0, stream>>>(xpT, spec, spec_bf16, yT);

    // 6. transpose to output layout (B,T,D) f32
    transpose_out<<<dim3(4096 / 32, 1024 / 32, B_DIM), 256, 0, stream>>>(yT, out);
}

// Round 20
// 667.634 us; speedup vs baseline: 1.2593x; 1.0588x over previous
//
#include <hip/hip_runtime.h>
#include <math.h>

#define T_LEN 4096
#define D_DIM 1024
#define B_DIM 4
#define N_STAGES 3
#define FT 512          // threads for both FFT kernels (512 => 128-VGPR natural cap)

typedef unsigned short bf16_t;
typedef __bf16 bf16x8 __attribute__((ext_vector_type(8)));
typedef float f32x4 __attribute__((ext_vector_type(4)));

// LDS bank swizzle at float2 granularity: i ^ ((i>>4)&15) — R10/R15-verified
// conflict floor (9.9e6 vs 2.6-3.5e7 for padded variants).
#define SW(i) ((i) ^ ((((unsigned)(i)) >> 4) & 15))

// ---------------------------------------------------------------- helpers
__device__ __forceinline__ bf16_t f2bf(float f) {
    union { float f; unsigned u; } v; v.f = f;
    unsigned r = v.u + 0x7FFFu + ((v.u >> 16) & 1u);   // round-nearest-even
    return (bf16_t)(r >> 16);
}
__device__ __forceinline__ float bf2f(bf16_t h) {
    union { unsigned u; float f; } v; v.u = ((unsigned)h) << 16;
    return v.f;
}
__device__ __forceinline__ float2 cmul(float2 a, float2 b) {
    return make_float2(a.x * b.x - a.y * b.y, a.x * b.y + a.y * b.x);
}
__device__ __forceinline__ float2 cadd(float2 a, float2 b) { return make_float2(a.x + b.x, a.y + b.y); }
__device__ __forceinline__ float2 csub(float2 a, float2 b) { return make_float2(a.x - b.x, a.y - b.y); }
__device__ __forceinline__ float2 conjf2(float2 a) { return make_float2(a.x, -a.y); }

#define GLOAD_LDS16(gp, lp) __builtin_amdgcn_global_load_lds( \
    (const __attribute__((address_space(1))) void*)(gp),      \
    (__attribute__((address_space(3))) void*)(lp), 16, 0, 0)

// ---------------------------------------------------------------- pos encoding (bf16 out)
__global__ __launch_bounds__(256) void pos_kernel(bf16_t* __restrict__ posbf) {
    int idx = blockIdx.x * 256 + threadIdx.x;
    int t = idx >> 10;
    int k = idx & 1023;
    float e = (float)(k & ~1) / (float)D_DIM;
    float r = exp2f(-e * 13.287712379549449f);          // 10000^-e
    float angle = (float)t * r;
    float v = (k & 1) ? cosf(angle) : sinf(angle);
    posbf[idx] = f2bf(v);
}

// ---------------------------------------------------------------- f32 -> bf16 copy
__global__ __launch_bounds__(256) void f32_to_bf16_kernel(const float* __restrict__ in,
                                                          bf16_t* __restrict__ out, int n8) {
    int i = blockIdx.x * 256 + threadIdx.x;
    if (i >= n8) return;
    float4 a = ((const float4*)in)[i * 2];
    float4 b = ((const float4*)in)[i * 2 + 1];
    ((ushort4*)out)[i * 2]     = make_ushort4(f2bf(a.x), f2bf(a.y), f2bf(a.z), f2bf(a.w));
    ((ushort4*)out)[i * 2 + 1] = make_ushort4(f2bf(b.x), f2bf(b.y), f2bf(b.z), f2bf(b.w));
}

// ---------------------------------------------------------------- W [K][N] f32 -> WT [N][K] bf16
__global__ __launch_bounds__(256) void transpose_to_bf16(const float* __restrict__ in,
                                                         bf16_t* __restrict__ out, int K, int N) {
    __shared__ float tile[32][33];
    const int n0 = blockIdx.x * 32;
    const int k0 = blockIdx.y * 32;
    const int tx = threadIdx.x & 31;
    const int ty = threadIdx.x >> 5;
    for (int i = ty; i < 32; i += 8)
        tile[i][tx] = in[(size_t)(k0 + i) * N + n0 + tx];
    __syncthreads();
    for (int i = ty; i < 32; i += 8)
        out[(size_t)(n0 + i) * K + k0 + tx] = f2bf(tile[tx][i]);
}

// ---------------------------------------------------------------- bf16 MFMA GEMM (m97 structure)
template <int MODE>
__global__ __launch_bounds__(256) void mfma_gemm(const bf16_t* __restrict__ A,
                                                 const bf16_t* __restrict__ BT,
                                                 const float* __restrict__ bias,
                                                 void* __restrict__ outv,
                                                 int M, int N, int K, int nbx) {
    constexpr int SMEM_BYTES = (MODE == 0) ? (128 * 136 * 2) : (128 * 132 * 4);
    __shared__ __align__(16) char smem[SMEM_BYTES];
    bf16_t* As = (bf16_t*)smem;
    bf16_t* Bs = (bf16_t*)(smem + 8192);

    const int tid = threadIdx.x;
    const int lane = tid & 63;
    const int w = tid >> 6;
    const int wr = w >> 1, wc = w & 1;

    const int nwg = gridDim.x;
    const int q = nwg >> 3;
    const int swz = (blockIdx.x & 7) * q + (blockIdx.x >> 3);
    const int by = swz / nbx, bx = swz - by * nbx;
    const int row0 = by * 128, col0 = bx * 128;

    f32x4 acc[4][4];
#pragma unroll
    for (int m = 0; m < 4; ++m)
#pragma unroll
        for (int n = 0; n < 4; ++n) acc[m][n] = (f32x4)(0.0f);

    int offs[2], rr[2], kk8[2];
#pragma unroll
    for (int c = 0; c < 2; ++c) {
        offs[c] = (w * 2 + c) * 1024 + lane * 16;
        rr[c] = offs[c] >> 6;
        kk8[c] = ((offs[c] >> 4) & 3) * 8;
    }

    for (int k0 = 0; k0 < K; k0 += 32) {
#pragma unroll
        for (int c = 0; c < 2; ++c) {
            const bf16_t* gA = A + (size_t)(row0 + rr[c]) * K + k0 + kk8[c];
            GLOAD_LDS16(gA, As + (w * 2 + c) * 512);
            const bf16_t* gB = BT + (size_t)(col0 + rr[c]) * K + k0 + kk8[c];
            GLOAD_LDS16(gB, Bs + (w * 2 + c) * 512);
        }
        __syncthreads();

        bf16x8 af[4], bfr[4];
#pragma unroll
        for (int m = 0; m < 4; ++m)
            af[m] = *(const bf16x8*)&As[(wr * 64 + m * 16 + (lane & 15)) * 32 + (lane >> 4) * 8];
#pragma unroll
        for (int n = 0; n < 4; ++n)
            bfr[n] = *(const bf16x8*)&Bs[(wc * 64 + n * 16 + (lane & 15)) * 32 + (lane >> 4) * 8];
#pragma unroll
        for (int m = 0; m < 4; ++m)
#pragma unroll
            for (int n = 0; n < 4; ++n)
                acc[m][n] = __builtin_amdgcn_mfma_f32_16x16x32_bf16(af[m], bfr[n], acc[m][n], 0, 0, 0);
        __syncthreads();
    }

    if (MODE == 0) {
        bf16_t* Cs = (bf16_t*)smem;           // [128 cols][pitch 136]
#pragma unroll
        for (int m = 0; m < 4; ++m)
#pragma unroll
            for (int n = 0; n < 4; ++n) {
                int cl = wc * 64 + n * 16 + (lane & 15);
                int rlb = wr * 64 + m * 16 + ((lane >> 4) << 2);
                float bb = bias[col0 + cl];
#pragma unroll
                for (int j = 0; j < 4; ++j)
                    Cs[cl * 136 + rlb + j] = f2bf(acc[m][n][j] + bb);
            }
        __syncthreads();
        int dl = tid >> 1, th = tid & 1;
        int cc = col0 + dl;
        int s = cc >> 10, d = cc & 1023;
        int b = row0 >> 12;
        int t0 = (row0 & 4095) + th * 64;
        uint4* dst = (uint4*)&((bf16_t*)outv)[((size_t)(s * 4 + b) * 1024 + d) * 4096 + t0];
        const uint4* src = (const uint4*)&Cs[dl * 136 + th * 64];
#pragma unroll
        for (int j = 0; j < 8; ++j) dst[j] = src[j];
    } else {
        float* CsF = (float*)smem;            // [128 cols][pitch 132]
#pragma unroll
        for (int m = 0; m < 4; ++m)
#pragma unroll
            for (int n = 0; n < 4; ++n) {
                int cl = wc * 64 + n * 16 + (lane & 15);
                int rlb = wr * 64 + m * 16 + ((lane >> 4) << 2);
                float bb = bias[col0 + cl];
#pragma unroll
                for (int j = 0; j < 4; ++j)
                    CsF[cl * 132 + rlb + j] = acc[m][n][j] + bb;
            }
        __syncthreads();
        int dl = tid >> 1, th = tid & 1;
        int cc = col0 + dl;
        uint4* dst = (uint4*)&((float*)outv)[(size_t)cc * 4096 + row0 + th * 64];
        const uint4* src = (const uint4*)&CsF[dl * 132 + th * 64];
#pragma unroll
        for (int j = 0; j < 16; ++j) dst[j] = src[j];
    }
}

// ---------------------------------------------------------------- radix-8 DFT building blocks
template <int INV>
__device__ __forceinline__ void bfly4(float2& a, float2& b, float2& c, float2& d) {
    float2 t0 = cadd(a, c), t1 = csub(a, c), t2 = cadd(b, d), t3 = csub(b, d);
    float2 it3 = INV ? make_float2(-t3.y, t3.x) : make_float2(t3.y, -t3.x);
    a = cadd(t0, t2); b = cadd(t1, it3); c = csub(t0, t2); d = csub(t1, it3);
}

// in-register DFT-8; on return x[q] = F_q (natural order)
template <int INV>
__device__ __forceinline__ void dft8(float2 (&x)[8]) {
    bfly4<INV>(x[0], x[2], x[4], x[6]);
    bfly4<INV>(x[1], x[3], x[5], x[7]);
    const float s2 = 0.70710678118654752f;
    const float2 o1 = INV ? make_float2(s2, s2) : make_float2(s2, -s2);
    const float2 o3 = INV ? make_float2(-s2, s2) : make_float2(-s2, -s2);
    x[3] = cmul(x[3], o1);
    x[5] = INV ? make_float2(-x[5].y, x[5].x) : make_float2(x[5].y, -x[5].x);
    x[7] = cmul(x[7], o3);
    float2 F0 = cadd(x[0], x[1]), F4 = csub(x[0], x[1]);
    float2 F1 = cadd(x[2], x[3]), F5 = csub(x[2], x[3]);
    float2 F2 = cadd(x[4], x[5]), F6 = csub(x[4], x[5]);
    float2 F3 = cadd(x[6], x[7]), F7 = csub(x[6], x[7]);
    x[0] = F0; x[1] = F1; x[2] = F2; x[3] = F3;
    x[4] = F4; x[5] = F5; x[6] = F6; x[7] = F7;
}

// Pass twiddle base: W_4096^jm = Wu[2*jm]  (Wu[k] = exp(-i*pi*k/4096))
// ---------------------------------------------------------------- single-seq radix-8 pass (filter kernel, 512 thr)
template <int INV, int M>
__device__ __forceinline__ void r8_pass(float2* __restrict__ s, const float2* __restrict__ Wu) {
    const int p = threadIdx.x;
    const int r = p & (M - 1);
    const int jm = p - r;
    float2 x[8];
#pragma unroll
    for (int c = 0; c < 8; ++c) x[c] = s[SW(p + 512 * c)];
    __syncthreads();
    dft8<INV>(x);
    const int base = 8 * jm + r;
    if (M == 512) {
#pragma unroll
        for (int q = 0; q < 8; ++q) s[SW(base + q * 512)] = x[q];
    } else {
        float2 w1 = Wu[2 * jm];
        if (INV) w1.y = -w1.y;
        float2 w2 = cmul(w1, w1);
        float2 w3 = cmul(w2, w1);
        float2 w4 = cmul(w2, w2);
        s[SW(base)]         = x[0];
        s[SW(base + M)]     = cmul(w1, x[1]);
        s[SW(base + 2 * M)] = cmul(w2, x[2]);
        s[SW(base + 3 * M)] = cmul(w3, x[3]);
        s[SW(base + 4 * M)] = cmul(w4, x[4]);
        s[SW(base + 5 * M)] = cmul(cmul(w4, w1), x[5]);
        s[SW(base + 6 * M)] = cmul(cmul(w4, w2), x[6]);
        s[SW(base + 7 * M)] = cmul(cmul(w4, w3), x[7]);
    }
    __syncthreads();
}

template <int INV>
__device__ __forceinline__ void fft4096_ip(float2* __restrict__ s, const float2* __restrict__ Wu) {
    r8_pass<INV, 1>(s, Wu);
    r8_pass<INV, 8>(s, Wu);
    r8_pass<INV, 64>(s, Wu);
    r8_pass<INV, 512>(s, Wu);
}

// ---------------------------------------------------------------- 4-seq pass, 512 thr, two x[2][8] sub-steps
// Thread owns butterfly p for ALL 4 seqs: pair {0,1} then pair {2,3}.
// Live regs per sub-step: 32 data + 14 twiddle + addr ~ 85 < 128-VGPR natural
// cap of 512-thread blocks (R14 verified: VGPR=128, no spill).
// Barrier schedule (2/pass): R01 | bar | W01,R23 | bar | W23 | [next R01...]
// Cross-segment overlaps are region-disjoint.
template <int INV, int M>
__device__ __forceinline__ void r8_pass4s(float2 (*__restrict__ s)[4096],
                                          const float2* __restrict__ Wu) {
    const int p = threadIdx.x;              // 0..511
    const int r = p & (M - 1);
    const int jm = p - r;
    const int base = 8 * jm + r;
    float2 w1, w2, w3, w4, w5, w6, w7;
    if (M != 512) {                         // computed once, shared by 4 seqs
        w1 = Wu[2 * jm];
        if (INV) w1.y = -w1.y;
        w2 = cmul(w1, w1); w3 = cmul(w2, w1); w4 = cmul(w2, w2);
        w5 = cmul(w4, w1); w6 = cmul(w4, w2); w7 = cmul(w4, w3);
    }
    // sub-step A: seqs {0,1}
    {
        float2 x[2][8];
#pragma unroll
        for (int e = 0; e < 2; ++e)
#pragma unroll
            for (int c = 0; c < 8; ++c) x[e][c] = s[e][SW(p + 512 * c)];
        __syncthreads();                    // prior-pass W23 + our R01 complete
#pragma unroll
        for (int e = 0; e < 2; ++e) {
            dft8<INV>(x[e]);
            if (M == 512) {
#pragma unroll
                for (int q = 0; q < 8; ++q) s[e][SW(base + q * 512)] = x[e][q];
            } else {
                s[e][SW(base)]         = x[e][0];
                s[e][SW(base + M)]     = cmul(w1, x[e][1]);
                s[e][SW(base + 2 * M)] = cmul(w2, x[e][2]);
                s[e][SW(base + 3 * M)] = cmul(w3, x[e][3]);
                s[e][SW(base + 4 * M)] = cmul(w4, x[e][4]);
                s[e][SW(base + 5 * M)] = cmul(w5, x[e][5]);
                s[e][SW(base + 6 * M)] = cmul(w6, x[e][6]);
                s[e][SW(base + 7 * M)] = cmul(w7, x[e][7]);
            }
        }
    }
    // sub-step B: seqs {2,3} (reads overlap W01 in flight: disjoint regions)
    {
        float2 y[2][8];
#pragma unroll
        for (int e = 0; e < 2; ++e)
#pragma unroll
            for (int c = 0; c < 8; ++c) y[e][c] = s[2 + e][SW(p + 512 * c)];
        __syncthreads();                    // W01 + R23 complete
#pragma unroll
        for (int e = 0; e < 2; ++e) {
            dft8<INV>(y[e]);
            if (M == 512) {
#pragma unroll
                for (int q = 0; q < 8; ++q) s[2 + e][SW(base + q * 512)] = y[e][q];
            } else {
                s[2 + e][SW(base)]         = y[e][0];
                s[2 + e][SW(base + M)]     = cmul(w1, y[e][1]);
                s[2 + e][SW(base + 2 * M)] = cmul(w2, y[e][2]);
                s[2 + e][SW(base + 3 * M)] = cmul(w3, y[e][3]);
                s[2 + e][SW(base + 4 * M)] = cmul(w4, y[e][4]);
                s[2 + e][SW(base + 5 * M)] = cmul(w5, y[e][5]);
                s[2 + e][SW(base + 6 * M)] = cmul(w6, y[e][6]);
                s[2 + e][SW(base + 7 * M)] = cmul(w7, y[e][7]);
            }
        }
    }
    // no trailing barrier: next pass's R01 is region-disjoint from W23
}

template <int INV>
__device__ __forceinline__ void fft4096_ip4s(float2 (*__restrict__ s)[4096],
                                             const float2* __restrict__ Wu) {
    r8_pass4s<INV, 1>(s, Wu);
    r8_pass4s<INV, 8>(s, Wu);
    r8_pass4s<INV, 64>(s, Wu);
    r8_pass4s<INV, 512>(s, Wu);
    __syncthreads();                        // drain W23 of last pass before consumers
}

// Wu[k] = exp(-pi*i*k/4096), k in [0,2048). sincos OUTSIDE loops (proven-safe).
__device__ __forceinline__ void init_wu(float2* __restrict__ Wu) {
    const int tid = threadIdx.x;
#pragma unroll
    for (int u = 0; u < 4; ++u) {
        int k = u * FT + tid;
        float sn, cs;
        __sincosf((float)k * -7.669903939428206e-4f, &sn, &cs);      // -pi/4096
        Wu[k] = make_float2(cs, sn);
    }
}

// spec accessors (half-spectrum rows of 4097 complex, f32 or bf16 pairs)
__device__ __forceinline__ float2 spec_load(const void* spec, int bf, size_t row, int k) {
    if (bf) {
        ushort2 h = ((const ushort2*)spec)[row * 4097 + k];
        return make_float2(bf2f(h.x), bf2f(h.y));
    }
    return ((const float2*)spec)[row * 4097 + k];
}
__device__ __forceinline__ void spec_store(void* spec, int bf, size_t row, int k, float2 v) {
    if (bf) ((ushort2*)spec)[row * 4097 + k] = make_ushort2(f2bf(v.x), f2bf(v.y));
    else    ((float2*)spec)[row * 4097 + k] = v;
}

// ---------------------------------------------------------------- filter spectra (packed real FFT)
// Plain __launch_bounds__ ONLY — extra occupancy hints squeeze the allocator (R6/R7).
__global__ __launch_bounds__(FT)
void filter_fft_kernel(const float* __restrict__ fT,
                       void* __restrict__ specv,
                       int spec_bf16) {
    __shared__ __align__(16) float2 sA[4096];
    __shared__ __align__(16) float2 Wu[2048];
    const int tid = threadIdx.x;
    const size_t row = blockIdx.x;          // i*1024 + d
    init_wu(Wu);
    const float4* f4 = (const float4*)&fT[row * T_LEN];
#pragma unroll
    for (int u = 0; u < 2; ++u) {
        int j = u * FT + tid;               // 0..1023
        float4 v = f4[j];
        sA[SW(2 * j)]     = make_float2(v.x, v.y);
        sA[SW(2 * j + 1)] = make_float2(v.z, v.w);
    }
#pragma unroll
    for (int u = 0; u < 4; ++u) {
        int n = 2048 + u * FT + tid;
        sA[SW(n)] = make_float2(0.0f, 0.0f);
    }
    __syncthreads();
    fft4096_ip<0>(sA, Wu);
    // untangle: F[k] = Ye + W_8192^k * Yo ; F[4096-k] = conj(Ye - W^k Yo)
#pragma unroll
    for (int u = 0; u < 4; ++u) {
        int s = u * FT + tid;
        if (s < 2047) {
            int k = s + 1, nk = 4096 - k;
            float2 Zk = sA[SW(k)], Zn = sA[SW(nk)];
            float2 Ye = make_float2(0.5f * (Zk.x + Zn.x), 0.5f * (Zk.y - Zn.y));
            float2 Yo = make_float2(0.5f * (Zk.y + Zn.y), -0.5f * (Zk.x - Zn.x));
            float2 w = Wu[k];
            float2 wYo = cmul(w, Yo);
            spec_store(specv, spec_bf16, row, k, cadd(Ye, wYo));
            spec_store(specv, spec_bf16, row, nk, conjf2(csub(Ye, wYo)));
        }
    }
    if (tid == 0) {
        float2 Z0 = sA[SW(0)];
        spec_store(specv, spec_bf16, row, 0,    make_float2(Z0.x + Z0.y, 0.0f));
        spec_store(specv, spec_bf16, row, 4096, make_float2(Z0.x - Z0.y, 0.0f));
        spec_store(specv, spec_bf16, row, 2048, conjf2(sA[SW(2048)]));
    }
}

// ---------------------------------------------------------------- fused 3-stage conv, 4-batched, 512 thr
// Block = one d; 4 sequences. LDS: 4*4096*8 + 16384 = 147,456 B (< 160 KiB cap).
__global__ __launch_bounds__(FT)
void conv_kernel(const bf16_t* __restrict__ xpT,
                 const void* __restrict__ specv,
                 int spec_bf16,
                 bf16_t* __restrict__ yT) {
    __shared__ __align__(16) float2 sA[4][4096];
    __shared__ __align__(16) float2 Wu[2048];
    const int tid = threadIdx.x;
    const int d = blockIdx.x;               // 0..1023
    init_wu(Wu);

#pragma unroll
    for (int bb = 0; bb < 4; ++bb) {
        const ushort4* y4 = (const ushort4*)&xpT[((size_t)bb * 1024 + d) * T_LEN];
#pragma unroll
        for (int u = 0; u < 2; ++u) {
            int j = u * FT + tid;           // 0..1023 ushort4
            ushort4 h = y4[j];
            sA[bb][SW(2 * j)]     = make_float2(bf2f(h.x), bf2f(h.y));
            sA[bb][SW(2 * j + 1)] = make_float2(bf2f(h.z), bf2f(h.w));
        }
#pragma unroll
        for (int u = 0; u < 4; ++u) {
            int n = 2048 + u * FT + tid;
            sA[bb][SW(n)] = make_float2(0.0f, 0.0f);
        }
    }
    __syncthreads();

    const float scale = 1.0f / 4096.0f;
    for (int st = 0; st < N_STAGES; ++st) {
        fft4096_ip4s<0>(sA, Wu);                      // forward, in place (4 seqs)
        const size_t row = (size_t)st * 1024 + d;
        // untangle -> Y, multiply by F, repack (spec row shared across 4 seqs)
#pragma unroll
        for (int u = 0; u < 4; ++u) {
            int s = u * FT + tid;
            if (s < 2047) {
                int k = s + 1, nk = 4096 - k;
                float2 w = Wu[k];
                float2 cw = conjf2(w);
                float2 Fk = spec_load(specv, spec_bf16, row, k);
                float2 Fn = spec_load(specv, spec_bf16, row, nk);
#pragma unroll
                for (int bb = 0; bb < 4; ++bb) {
                    float2 Zk = sA[bb][SW(k)], Zn = sA[bb][SW(nk)];
                    float2 Ye = make_float2(0.5f * (Zk.x + Zn.x), 0.5f * (Zk.y - Zn.y));
                    float2 Yo = make_float2(0.5f * (Zk.y + Zn.y), -0.5f * (Zk.x - Zn.x));
                    float2 wYo = cmul(w, Yo);
                    float2 Yk = cadd(Ye, wYo);
                    float2 Ynk = conjf2(csub(Ye, wYo));
                    float2 Hk = cmul(Yk, Fk);
                    float2 Hn = cmul(Ynk, Fn);
                    float2 He = make_float2(0.5f * (Hk.x + Hn.x), 0.5f * (Hk.y - Hn.y));
                    float2 Hd = make_float2(0.5f * (Hk.x - Hn.x), 0.5f * (Hk.y + Hn.y));
                    float2 Ho = cmul(cw, Hd);
                    sA[bb][SW(k)]  = make_float2(He.x - Ho.y, He.y + Ho.x);
                    sA[bb][SW(nk)] = make_float2(He.x + Ho.y, Ho.x - He.y);
                }
            }
        }
        if (tid == 0) {
            float2 F0 = spec_load(specv, spec_bf16, row, 0);
            float2 FN = spec_load(specv, spec_bf16, row, 4096);
            float2 F2 = spec_load(specv, spec_bf16, row, 2048);
#pragma unroll
            for (int bb = 0; bb < 4; ++bb) {
                float2 Z0 = sA[bb][SW(0)];
                float Y0 = Z0.x + Z0.y, YN = Z0.x - Z0.y;
                float2 H0 = make_float2(Y0 * F0.x, Y0 * F0.y);
                float2 HN = make_float2(YN * FN.x, YN * FN.y);
                float2 He0 = make_float2(0.5f * (H0.x + HN.x), 0.5f * (H0.y + HN.y));
                float2 Ho0 = make_float2(0.5f * (H0.x - HN.x), 0.5f * (H0.y - HN.y));
                sA[bb][SW(0)] = make_float2(He0.x - Ho0.y, He0.y + Ho0.x);
                float2 H2 = cmul(conjf2(sA[bb][SW(2048)]), F2);
                sA[bb][SW(2048)] = conjf2(H2);
            }
        }
        __syncthreads();
        fft4096_ip4s<1>(sA, Wu);                      // inverse (unnormalized), in place

        if (st < N_STAGES - 1) {
#pragma unroll
            for (int bb = 0; bb < 4; ++bb) {
                const ushort4* g4 = (const ushort4*)&xpT[((size_t)((st + 1) * 4 + bb) * 1024 + d) * T_LEN];
#pragma unroll
                for (int u = 0; u < 2; ++u) {
                    int j = u * FT + tid;
                    ushort4 h = g4[j];
                    float2 v0 = sA[bb][SW(2 * j)], v1 = sA[bb][SW(2 * j + 1)];
                    sA[bb][SW(2 * j)]     = make_float2(v0.x * scale * bf2f(h.x), v0.y * scale * bf2f(h.y));
                    sA[bb][SW(2 * j + 1)] = make_float2(v1.x * scale * bf2f(h.z), v1.y * scale * bf2f(h.w));
                }
#pragma unroll
                for (int u = 0; u < 4; ++u) {
                    int n = 2048 + u * FT + tid;
                    sA[bb][SW(n)] = make_float2(0.0f, 0.0f);
                }
            }
            __syncthreads();
        } else {
#pragma unroll
            for (int bb = 0; bb < 4; ++bb) {
                const ushort4* g4 = (const ushort4*)&xpT[((size_t)((st + 1) * 4 + bb) * 1024 + d) * T_LEN];
                ushort4* yrow = (ushort4*)&yT[((size_t)bb * 1024 + d) * T_LEN];
#pragma unroll
                for (int u = 0; u < 2; ++u) {
                    int j = u * FT + tid;
                    ushort4 h = g4[j];
                    float2 v0 = sA[bb][SW(2 * j)], v1 = sA[bb][SW(2 * j + 1)];
                    yrow[j] = make_ushort4(f2bf(v0.x * scale * bf2f(h.x)),
                                           f2bf(v0.y * scale * bf2f(h.y)),
                                           f2bf(v1.x * scale * bf2f(h.z)),
                                           f2bf(v1.y * scale * bf2f(h.w)));
                }
            }
        }
    }
}

// ---------------------------------------------------------------- yT (B,D,T) bf16 -> out (B,T,D) f32
__global__ __launch_bounds__(256) void transpose_out(const bf16_t* __restrict__ yT,
                                                     float* __restrict__ out) {
    __shared__ float tile[32][33];
    const int tb = blockIdx.z;
    const int t0 = blockIdx.x * 32;
    const int d0 = blockIdx.y * 32;
    const int tx = threadIdx.x & 31;
    const int ty = threadIdx.x >> 5;
    for (int i = ty; i < 32; i += 8)
        tile[i][tx] = bf2f(yT[((size_t)tb * 1024 + d0 + i) * 4096 + t0 + tx]);
    __syncthreads();
    for (int i = ty; i < 32; i += 8)
        out[((size_t)tb * 4096 + t0 + i) * 1024 + d0 + tx] = tile[tx][i];
}

// ---------------------------------------------------------------- launch
extern "C" void kernel_launch(void* const* d_in, const int* in_sizes, int n_in,
                              void* d_out, int out_size, void* d_ws, size_t ws_size,
                              hipStream_t stream) {
    const float* X   = (const float*)d_in[0];
    const float* Wp  = (const float*)d_in[1];
    const float* bp  = (const float*)d_in[2];
    const float* Wf  = (const float*)d_in[3];
    const float* bfv = (const float*)d_in[4];
    float* out = (float*)d_out;
    char* ws = (char*)d_ws;

    const size_t XPT_BYTES  = (size_t)134217728;
    const size_t SPEC_F32_B = (size_t)3 * 1024 * 4097 * 8;
    const size_t SPEC_BF_B  = (size_t)3 * 1024 * 4097 * 4;
    const size_t XBF_BYTES  = (size_t)33554432;
    const size_t WPT_BYTES  = (size_t)8388608;

    bf16_t* xpT   = (bf16_t*)ws;
    bf16_t* posbf = (bf16_t*)ws;
    bf16_t* WfT   = (bf16_t*)(ws + 16777216);
    float*  fT    = (float*)(ws + 33554432);
    void*   spec  = (void*)(ws + XPT_BYTES);

    int spec_bf16;
    size_t spec_bytes;
    if (ws_size >= XPT_BYTES + SPEC_F32_B + XBF_BYTES + WPT_BYTES) {
        spec_bf16 = 0; spec_bytes = SPEC_F32_B;
    } else {
        spec_bf16 = 1; spec_bytes = SPEC_BF_B;
    }
    bf16_t* Xbf = (bf16_t*)(ws + XPT_BYTES + spec_bytes);
    bf16_t* WpT = (bf16_t*)(ws + XPT_BYTES + spec_bytes + XBF_BYTES);
    bf16_t* yT  = Xbf;   // reuse after GEMM2 consumes Xbf

    // 1. positional encoding (bf16)
    pos_kernel<<<(T_LEN * D_DIM) / 256, 256, 0, stream>>>(posbf);

    // 2. WfT = transpose(Wf); f = pos @ Wf + bf -> fT f32 [(i*D+d)][t]
    transpose_to_bf16<<<dim3(3072 / 32, 1024 / 32), 256, 0, stream>>>(Wf, WfT, 1024, 3072);
    mfma_gemm<1><<<768, 256, 0, stream>>>(posbf, WfT, bfv, fT, 4096, 3072, 1024, 24);

    // 3. filter spectra (packed real FFT, radix-8 in-place, table twiddles)
    filter_fft_kernel<<<N_STAGES * D_DIM, FT, 0, stream>>>(fT, spec, spec_bf16);

    // 4. Xbf, WpT ; xp = X @ Wp + bp -> xpT bf16
    f32_to_bf16_kernel<<<8192, 256, 0, stream>>>(X, Xbf, 2097152);
    transpose_to_bf16<<<dim3(4096 / 32, 1024 / 32), 256, 0, stream>>>(Wp, WpT, 1024, 4096);
    mfma_gemm<0><<<4096, 256, 0, stream>>>(Xbf, WpT, bp, xpT, 16384, 4096, 1024, 32);

    // 5. fused 3-stage FFT conv + gating, 4-batched per d, 512 thr -> yT
    conv_kernel<<<D_DIM, FT, 0, stream>>>(xpT, spec, spec_bf16, yT);

    // 6. transpose to output layout (B,T,D) f32
    transpose_out<<<dim3(4096 / 32, 1024 / 32, B_DIM), 256, 0, stream>>>(yT, out);
}